// Round 2
// baseline (642.595 us; speedup 1.0000x reference)
//
#include <hip/hip_runtime.h>
#include <hip/hip_bf16.h>
#include <math.h>

#define HS 1024      // hidden size
#define IS 2048      // intermediate size
#define NHEAD 16
#define HDIM 64
#define NEXP 8
#define BATCH 2
#define SEQ 1024
#define NTOK (BATCH*SEQ)     // 2048 tokens
#define NASSIGN (NTOK*2)     // 4096 (token, expert) assignments
#define QKVW 3072            // fused qkv row width
#define PAD 72               // LDS row stride for attn (bf16 elems)
#define MAXBLK 40            // max 128-row blocks over all experts

typedef short bf16x8 __attribute__((ext_vector_type(8)));
typedef float f32x4  __attribute__((ext_vector_type(4)));
typedef unsigned short u16x8 __attribute__((ext_vector_type(8)));
typedef unsigned short u16x4 __attribute__((ext_vector_type(4)));

// async global->LDS, 16B per lane; lds dest = base + lane*16 (wave-uniform base)
__device__ __forceinline__ void ldsdma16(void* lds, const void* gp) {
    __builtin_amdgcn_global_load_lds(
        (const __attribute__((address_space(1))) void*)gp,
        (__attribute__((address_space(3))) void*)lds, 16, 0, 0);
}

// ---------------------------------------------------------------- rmsnorm -> split bf16 (hi+lo)
__global__ void rmsnorm_split(const float* __restrict__ x, const float* __restrict__ w,
                              __hip_bfloat16* __restrict__ oh, __hip_bfloat16* __restrict__ ol) {
    int t = blockIdx.x;
    int tid = threadIdx.x;
    const float* row = x + (size_t)t * HS;
    float4 v4 = *(const float4*)(row + tid * 4);
    float ss = v4.x * v4.x + v4.y * v4.y + v4.z * v4.z + v4.w * v4.w;
    for (int off = 32; off > 0; off >>= 1) ss += __shfl_down(ss, off);
    __shared__ float red[4];
    if ((tid & 63) == 0) red[tid >> 6] = ss;
    __syncthreads();
    float tot = red[0] + red[1] + red[2] + red[3];
    float rr = rsqrtf(tot / (float)HS + 1e-6f);
    float4 w4 = *(const float4*)(w + tid * 4);
    float vals[4] = {w4.x * v4.x * rr, w4.y * v4.y * rr, w4.z * v4.z * rr, w4.w * v4.w * rr};
    u16x4 h4, l4;
    #pragma unroll
    for (int j = 0; j < 4; j++) {
        __hip_bfloat16 hi = __float2bfloat16(vals[j]);
        __hip_bfloat16 lo = __float2bfloat16(vals[j] - __bfloat162float(hi));
        h4[j] = *(unsigned short*)&hi;
        l4[j] = *(unsigned short*)&lo;
    }
    *(u16x4*)&oh[(size_t)t * HS + tid * 4] = h4;
    *(u16x4*)&ol[(size_t)t * HS + tid * 4] = l4;
}

// ---------------------------------------------------------------- rmsnorm dual (fp32 + bf16)
__global__ void rmsnorm_dual(const float* __restrict__ x, const float* __restrict__ w,
                             float* __restrict__ outf, __hip_bfloat16* __restrict__ outb) {
    int t = blockIdx.x;
    int tid = threadIdx.x;
    const float* row = x + (size_t)t * HS;
    float4 v4 = *(const float4*)(row + tid * 4);
    float ss = v4.x * v4.x + v4.y * v4.y + v4.z * v4.z + v4.w * v4.w;
    for (int off = 32; off > 0; off >>= 1) ss += __shfl_down(ss, off);
    __shared__ float red[4];
    if ((tid & 63) == 0) red[tid >> 6] = ss;
    __syncthreads();
    float tot = red[0] + red[1] + red[2] + red[3];
    float rr = rsqrtf(tot / (float)HS + 1e-6f);
    float4 w4 = *(const float4*)(w + tid * 4);
    float4 o4 = make_float4(w4.x * v4.x * rr, w4.y * v4.y * rr, w4.z * v4.z * rr, w4.w * v4.w * rr);
    *(float4*)&outf[(size_t)t * HS + tid * 4] = o4;
    float vals[4] = {o4.x, o4.y, o4.z, o4.w};
    u16x4 b4;
    #pragma unroll
    for (int j = 0; j < 4; j++) {
        __hip_bfloat16 hi = __float2bfloat16(vals[j]);
        b4[j] = *(unsigned short*)&hi;
    }
    *(u16x4*)&outb[(size_t)t * HS + tid * 4] = b4;
}

// ---------------------------------------------------------------- fused 4-way transpose fp32 [1024][1024] -> split bf16 [C][R]
// z=0..2: wq/wk/wv -> qkvT at rowOff z*HS ; z=3: wo -> woT
__global__ __launch_bounds__(256) void transpose_split4(
        const float* __restrict__ wq, const float* __restrict__ wk,
        const float* __restrict__ wv, const float* __restrict__ wo,
        __hip_bfloat16* __restrict__ qkvh, __hip_bfloat16* __restrict__ qkvl,
        __hip_bfloat16* __restrict__ oh, __hip_bfloat16* __restrict__ ol) {
    int z = blockIdx.z;
    const float* src = (z == 0) ? wq : (z == 1) ? wk : (z == 2) ? wv : wo;
    __hip_bfloat16* dh = (z < 3) ? qkvh : oh;
    __hip_bfloat16* dl = (z < 3) ? qkvl : ol;
    int rowOff = (z < 3) ? z * HS : 0;
    const int R = HS, C = HS;
    __shared__ float tile[64][65];
    int c0 = blockIdx.x * 64, r0 = blockIdx.y * 64;
    int tx = threadIdx.x & 15, ty = threadIdx.x >> 4;
    #pragma unroll
    for (int p = 0; p < 4; p++) {
        int r = ty + p * 16;
        float4 v = *(const float4*)(src + (size_t)(r0 + r) * C + c0 + tx * 4);
        tile[r][tx * 4 + 0] = v.x; tile[r][tx * 4 + 1] = v.y;
        tile[r][tx * 4 + 2] = v.z; tile[r][tx * 4 + 3] = v.w;
    }
    __syncthreads();
    int cc0 = threadIdx.x >> 3, rr = (threadIdx.x & 7) * 8;
    #pragma unroll
    for (int p = 0; p < 2; p++) {
        int cc = cc0 + p * 32;
        u16x8 h8, l8;
        #pragma unroll
        for (int j = 0; j < 8; j++) {
            float v = tile[rr + j][cc];
            __hip_bfloat16 hi = __float2bfloat16(v);
            __hip_bfloat16 lo = __float2bfloat16(v - __bfloat162float(hi));
            h8[j] = *(unsigned short*)&hi;
            l8[j] = *(unsigned short*)&lo;
        }
        size_t o = (size_t)(rowOff + c0 + cc) * R + r0 + rr;
        *(u16x8*)&dh[o] = h8;
        *(u16x8*)&dl[o] = l8;
    }
}

// ---------------------------------------------------------------- transpose fp32 [R][C] -> bf16 [C][R], per expert z, 64x64 tiles
__global__ __launch_bounds__(256) void transpose_b64(const float* __restrict__ in,
                                                     __hip_bfloat16* __restrict__ outp,
                                                     int R, int C) {
    int e = blockIdx.z;
    const float* src = in + (size_t)e * R * C;
    __hip_bfloat16* dst = outp + (size_t)e * R * C;
    __shared__ float tile[64][65];
    int c0 = blockIdx.x * 64, r0 = blockIdx.y * 64;
    int tx = threadIdx.x & 15, ty = threadIdx.x >> 4;
    #pragma unroll
    for (int p = 0; p < 4; p++) {
        int r = ty + p * 16;
        float4 v = *(const float4*)(src + (size_t)(r0 + r) * C + c0 + tx * 4);
        tile[r][tx * 4 + 0] = v.x; tile[r][tx * 4 + 1] = v.y;
        tile[r][tx * 4 + 2] = v.z; tile[r][tx * 4 + 3] = v.w;
    }
    __syncthreads();
    int cc0 = threadIdx.x >> 3, rr = (threadIdx.x & 7) * 8;
    #pragma unroll
    for (int p = 0; p < 2; p++) {
        int cc = cc0 + p * 32;
        u16x8 b8;
        #pragma unroll
        for (int j = 0; j < 8; j++) {
            __hip_bfloat16 hi = __float2bfloat16(tile[rr + j][cc]);
            b8[j] = *(unsigned short*)&hi;
        }
        *(u16x8*)&dst[(size_t)(c0 + cc) * R + r0 + rr] = b8;
    }
}

// ---------------------------------------------------------------- split-bf16 GEMM, 128x64 tile, dbuf DMA
// C[M][N] = (Ah+Al)[M][K] @ (Bh+Bl)[N][K]^T (+resid), via Ah@Bh + Ah@Bl + Al@Bh
__global__ __launch_bounds__(256) void gemm_bf16x3(const __hip_bfloat16* __restrict__ Ah,
                                                   const __hip_bfloat16* __restrict__ Al,
                                                   const __hip_bfloat16* __restrict__ Bh,
                                                   const __hip_bfloat16* __restrict__ Bl,
                                                   const float* __restrict__ resid,
                                                   float* __restrict__ C,
                                                   int M, int N, int K) {
    __shared__ __align__(16) short Ahs[2][128][32];   // 16 KB
    __shared__ __align__(16) short Als[2][128][32];   // 16 KB
    __shared__ __align__(16) short Bhs[2][64][32];    // 8 KB
    __shared__ __align__(16) short Bls[2][64][32];    // 8 KB -> 48 KB total
    int bm = blockIdx.y * 128, bn = blockIdx.x * 64;
    int t = threadIdx.x;
    int wave = t >> 6, lane = t & 63;
    int wm = (wave & 1) * 64, wn = (wave >> 1) * 32;
    int fr = lane & 15, quad = lane >> 4;
    int rA = wave * 32;            // A rows staged by this wave
    int rB = wave * 16;            // B rows staged by this wave
    int srow = lane >> 2;
    int schunk = (lane & 3) ^ ((lane >> 3) & 3);   // xor-swizzled 16B chunk
    const __hip_bfloat16* pAh0 = Ah + (size_t)(bm + rA + srow) * K + schunk * 8;
    const __hip_bfloat16* pAh1 = pAh0 + (size_t)16 * K;
    const __hip_bfloat16* pAl0 = Al + (size_t)(bm + rA + srow) * K + schunk * 8;
    const __hip_bfloat16* pAl1 = pAl0 + (size_t)16 * K;
    const __hip_bfloat16* pBh  = Bh + (size_t)(bn + rB + srow) * K + schunk * 8;
    const __hip_bfloat16* pBl  = Bl + (size_t)(bn + rB + srow) * K + schunk * 8;
    int ca = (quad ^ ((fr >> 1) & 3)) * 8;         // swizzled frag col (shorts)

    ldsdma16(&Ahs[0][rA][0],      pAh0);
    ldsdma16(&Ahs[0][rA + 16][0], pAh1);
    ldsdma16(&Als[0][rA][0],      pAl0);
    ldsdma16(&Als[0][rA + 16][0], pAl1);
    ldsdma16(&Bhs[0][rB][0],      pBh);
    ldsdma16(&Bls[0][rB][0],      pBl);

    f32x4 acc[4][2] = {};
    int NIT = K >> 5;
    for (int it = 0; it < NIT; it++) {
        int cur = it & 1;
        __syncthreads();
        if (it + 1 < NIT) {
            int k1 = (it + 1) << 5;
            int nxt = cur ^ 1;
            ldsdma16(&Ahs[nxt][rA][0],      pAh0 + k1);
            ldsdma16(&Ahs[nxt][rA + 16][0], pAh1 + k1);
            ldsdma16(&Als[nxt][rA][0],      pAl0 + k1);
            ldsdma16(&Als[nxt][rA + 16][0], pAl1 + k1);
            ldsdma16(&Bhs[nxt][rB][0],      pBh + k1);
            ldsdma16(&Bls[nxt][rB][0],      pBl + k1);
        }
        bf16x8 ah[4], bh[2], x[4];
        #pragma unroll
        for (int i = 0; i < 4; i++) ah[i] = *(const bf16x8*)&Ahs[cur][wm + i * 16 + fr][ca];
        #pragma unroll
        for (int i = 0; i < 2; i++) bh[i] = *(const bf16x8*)&Bhs[cur][wn + i * 16 + fr][ca];
        #pragma unroll
        for (int mi = 0; mi < 4; mi++)
            #pragma unroll
            for (int ni = 0; ni < 2; ni++)
                acc[mi][ni] = __builtin_amdgcn_mfma_f32_16x16x32_bf16(ah[mi], bh[ni], acc[mi][ni], 0, 0, 0);
        #pragma unroll
        for (int i = 0; i < 2; i++) x[i] = *(const bf16x8*)&Bls[cur][wn + i * 16 + fr][ca];
        #pragma unroll
        for (int mi = 0; mi < 4; mi++)
            #pragma unroll
            for (int ni = 0; ni < 2; ni++)
                acc[mi][ni] = __builtin_amdgcn_mfma_f32_16x16x32_bf16(ah[mi], x[ni], acc[mi][ni], 0, 0, 0);
        #pragma unroll
        for (int i = 0; i < 4; i++) x[i] = *(const bf16x8*)&Als[cur][wm + i * 16 + fr][ca];
        #pragma unroll
        for (int mi = 0; mi < 4; mi++)
            #pragma unroll
            for (int ni = 0; ni < 2; ni++)
                acc[mi][ni] = __builtin_amdgcn_mfma_f32_16x16x32_bf16(x[mi], bh[ni], acc[mi][ni], 0, 0, 0);
    }
    int rq = quad * 4;
    #pragma unroll
    for (int mi = 0; mi < 4; mi++) {
        #pragma unroll
        for (int r = 0; r < 4; r++) {
            size_t rowo = (size_t)(bm + wm + mi * 16 + rq + r) * N + bn + wn;
            #pragma unroll
            for (int ni = 0; ni < 2; ni++) {
                float v = acc[mi][ni][r];
                size_t o = rowo + ni * 16 + fr;
                if (resid) v += resid[o];
                C[o] = v;
            }
        }
    }
}

// ---------------------------------------------------------------- RoPE + convert qkv fp32 -> split bf16 q,k,v
__global__ void rope_convert(const float* __restrict__ qkv, const float* __restrict__ fc,
                             __hip_bfloat16* __restrict__ qh, __hip_bfloat16* __restrict__ ql,
                             __hip_bfloat16* __restrict__ kh, __hip_bfloat16* __restrict__ kl,
                             __hip_bfloat16* __restrict__ vh, __hip_bfloat16* __restrict__ vl) {
    int t = blockIdx.x;
    int s = t & (SEQ - 1);
    const float* row = qkv + (size_t)t * QKVW;
    size_t ob = (size_t)t * HS;
    for (int p = threadIdx.x; p < 512; p += 256) {
        int hh = p >> 5, j = p & 31;
        int col = hh * 64 + 2 * j;
        float cr = fc[s * HDIM + 2 * j];
        float ci = fc[s * HDIM + 2 * j + 1];
        float a = row[col], b = row[col + 1];
        float r0 = a * cr - b * ci, r1 = a * ci + b * cr;
        __hip_bfloat16 h0 = __float2bfloat16(r0), h1 = __float2bfloat16(r1);
        qh[ob + col] = h0;     ql[ob + col]     = __float2bfloat16(r0 - __bfloat162float(h0));
        qh[ob + col + 1] = h1; ql[ob + col + 1] = __float2bfloat16(r1 - __bfloat162float(h1));
        a = row[1024 + col]; b = row[1024 + col + 1];
        r0 = a * cr - b * ci; r1 = a * ci + b * cr;
        h0 = __float2bfloat16(r0); h1 = __float2bfloat16(r1);
        kh[ob + col] = h0;     kl[ob + col]     = __float2bfloat16(r0 - __bfloat162float(h0));
        kh[ob + col + 1] = h1; kl[ob + col + 1] = __float2bfloat16(r1 - __bfloat162float(h1));
        r0 = row[2048 + col]; r1 = row[2048 + col + 1];
        h0 = __float2bfloat16(r0); h1 = __float2bfloat16(r1);
        vh[ob + col] = h0;     vl[ob + col]     = __float2bfloat16(r0 - __bfloat162float(h0));
        vh[ob + col + 1] = h1; vl[ob + col + 1] = __float2bfloat16(r1 - __bfloat162float(h1));
    }
}

// ---------------------------------------------------------------- split-K flash attention, MFMA split-bf16
__global__ __launch_bounds__(256) void attn_partial(
        const __hip_bfloat16* __restrict__ qh, const __hip_bfloat16* __restrict__ ql,
        const __hip_bfloat16* __restrict__ kh, const __hip_bfloat16* __restrict__ kl,
        const __hip_bfloat16* __restrict__ vh, const __hip_bfloat16* __restrict__ vl,
        float* __restrict__ po, float* __restrict__ pm_g, float* __restrict__ pl_g) {
    int c = blockIdx.x, qt = blockIdx.y;
    int nc = (qt + 4) >> 2;
    if (c >= nc) return;
    int bh = blockIdx.z;
    int b = bh >> 4, h = bh & 15;
    int t0 = c * 4, t1 = min(t0 + 4, qt + 1);
    int tid = threadIdx.x;
    int wave = tid >> 6, lane = tid & 63;
    int fr = lane & 15, quad = lane >> 4;
    int w16 = wave * 16;
    __shared__ __align__(16) short Qh[64][PAD], Ql[64][PAD];
    __shared__ __align__(16) short KPh[64][PAD], KPl[64][PAD];
    __shared__ __align__(16) short Vhs[64][PAD], Vls[64][PAD];
    size_t hoff = (size_t)h * HDIM;
    int sr = tid >> 2, sg = tid & 3;
    {
        const __hip_bfloat16* qp  = qh + (size_t)(b * SEQ + qt * 64 + sr) * HS + hoff;
        const __hip_bfloat16* qp2 = ql + (size_t)(b * SEQ + qt * 64 + sr) * HS + hoff;
        *(uint4*)&Qh[sr][sg * 8]       = *(const uint4*)(qp + sg * 8);
        *(uint4*)&Qh[sr][(sg + 4) * 8] = *(const uint4*)(qp + (sg + 4) * 8);
        *(uint4*)&Ql[sr][sg * 8]       = *(const uint4*)(qp2 + sg * 8);
        *(uint4*)&Ql[sr][(sg + 4) * 8] = *(const uint4*)(qp2 + (sg + 4) * 8);
    }
    f32x4 o[4] = {};
    float mrow[4], lrow[4];
    #pragma unroll
    for (int i = 0; i < 4; i++) { mrow[i] = -1e30f; lrow[i] = 0.f; }
    int key0 = (tid & 31) * 2, ds = tid >> 5;
    __syncthreads();

    for (int kt = t0; kt < t1; kt++) {
        int kbase = kt * 64;
        {
            const __hip_bfloat16* kp  = kh + (size_t)(b * SEQ + kbase + sr) * HS + hoff;
            const __hip_bfloat16* kp2 = kl + (size_t)(b * SEQ + kbase + sr) * HS + hoff;
            *(uint4*)&KPh[sr][sg * 8]       = *(const uint4*)(kp + sg * 8);
            *(uint4*)&KPh[sr][(sg + 4) * 8] = *(const uint4*)(kp + (sg + 4) * 8);
            *(uint4*)&KPl[sr][sg * 8]       = *(const uint4*)(kp2 + sg * 8);
            *(uint4*)&KPl[sr][(sg + 4) * 8] = *(const uint4*)(kp2 + (sg + 4) * 8);
        }
        {
            const __hip_bfloat16* v0 = vh + (size_t)(b * SEQ + kbase + key0) * HS + hoff + ds * 8;
            uint4 A = *(const uint4*)v0;
            uint4 Bv = *(const uint4*)(v0 + HS);
            const unsigned short* ap = (const unsigned short*)&A;
            const unsigned short* bp = (const unsigned short*)&Bv;
            #pragma unroll
            for (int j = 0; j < 8; j++)
                *(unsigned*)&Vhs[ds * 8 + j][key0] = (unsigned)ap[j] | ((unsigned)bp[j] << 16);
            const __hip_bfloat16* v2 = vl + (size_t)(b * SEQ + kbase + key0) * HS + hoff + ds * 8;
            uint4 A2 = *(const uint4*)v2;
            uint4 B2 = *(const uint4*)(v2 + HS);
            const unsigned short* ap2 = (const unsigned short*)&A2;
            const unsigned short* bp2 = (const unsigned short*)&B2;
            #pragma unroll
            for (int j = 0; j < 8; j++)
                *(unsigned*)&Vls[ds * 8 + j][key0] = (unsigned)ap2[j] | ((unsigned)bp2[j] << 16);
        }
        __syncthreads();

        f32x4 s[4] = {};
        #pragma unroll
        for (int ks = 0; ks < 2; ks++) {
            bf16x8 a_h = *(const bf16x8*)&Qh[w16 + fr][quad * 8 + ks * 32];
            bf16x8 a_l = *(const bf16x8*)&Ql[w16 + fr][quad * 8 + ks * 32];
            #pragma unroll
            for (int ni = 0; ni < 4; ni++) {
                bf16x8 b_h = *(const bf16x8*)&KPh[ni * 16 + fr][quad * 8 + ks * 32];
                bf16x8 b_l = *(const bf16x8*)&KPl[ni * 16 + fr][quad * 8 + ks * 32];
                s[ni] = __builtin_amdgcn_mfma_f32_16x16x32_bf16(a_h, b_h, s[ni], 0, 0, 0);
                s[ni] = __builtin_amdgcn_mfma_f32_16x16x32_bf16(a_h, b_l, s[ni], 0, 0, 0);
                s[ni] = __builtin_amdgcn_mfma_f32_16x16x32_bf16(a_l, b_h, s[ni], 0, 0, 0);
            }
        }
        int qg = qt * 64 + w16 + quad * 4;
        #pragma unroll
        for (int ni = 0; ni < 4; ni++) {
            int kg = kbase + ni * 16 + fr;
            #pragma unroll
            for (int r = 0; r < 4; r++)
                s[ni][r] = (kg > qg + r) ? -1e9f : s[ni][r] * 0.125f;
        }
        #pragma unroll
        for (int r = 0; r < 4; r++) {
            float mx = fmaxf(fmaxf(s[0][r], s[1][r]), fmaxf(s[2][r], s[3][r]));
            #pragma unroll
            for (int wd = 1; wd < 16; wd <<= 1) mx = fmaxf(mx, __shfl_xor(mx, wd));
            float nm = fmaxf(mrow[r], mx);
            float alpha = __expf(mrow[r] - nm);
            float rs = 0.f;
            #pragma unroll
            for (int ni = 0; ni < 4; ni++) { float e = __expf(s[ni][r] - nm); s[ni][r] = e; rs += e; }
            #pragma unroll
            for (int wd = 1; wd < 16; wd <<= 1) rs += __shfl_xor(rs, wd);
            lrow[r] = lrow[r] * alpha + rs;
            mrow[r] = nm;
            o[0][r] *= alpha; o[1][r] *= alpha; o[2][r] *= alpha; o[3][r] *= alpha;
        }
        __syncthreads();
        #pragma unroll
        for (int ni = 0; ni < 4; ni++)
            #pragma unroll
            for (int r = 0; r < 4; r++) {
                float pv = s[ni][r];
                __hip_bfloat16 hi = __float2bfloat16(pv);
                __hip_bfloat16 lo = __float2bfloat16(pv - __bfloat162float(hi));
                KPh[w16 + quad * 4 + r][ni * 16 + fr] = *(short*)&hi;
                KPl[w16 + quad * 4 + r][ni * 16 + fr] = *(short*)&lo;
            }
        #pragma unroll
        for (int ks = 0; ks < 2; ks++) {
            bf16x8 p_h = *(const bf16x8*)&KPh[w16 + fr][quad * 8 + ks * 32];
            bf16x8 p_l = *(const bf16x8*)&KPl[w16 + fr][quad * 8 + ks * 32];
            #pragma unroll
            for (int ni = 0; ni < 4; ni++) {
                bf16x8 v_h = *(const bf16x8*)&Vhs[ni * 16 + fr][quad * 8 + ks * 32];
                bf16x8 v_l = *(const bf16x8*)&Vls[ni * 16 + fr][quad * 8 + ks * 32];
                o[ni] = __builtin_amdgcn_mfma_f32_16x16x32_bf16(p_h, v_h, o[ni], 0, 0, 0);
                o[ni] = __builtin_amdgcn_mfma_f32_16x16x32_bf16(p_h, v_l, o[ni], 0, 0, 0);
                o[ni] = __builtin_amdgcn_mfma_f32_16x16x32_bf16(p_l, v_h, o[ni], 0, 0, 0);
            }
        }
        __syncthreads();
    }
    int pidx = (bh * 16 + qt) * 4 + c;
    float* pob = po + (size_t)pidx * 4096;
    #pragma unroll
    for (int ni = 0; ni < 4; ni++)
        #pragma unroll
        for (int r = 0; r < 4; r++)
            pob[(w16 + quad * 4 + r) * 64 + ni * 16 + fr] = o[ni][r];
    if (fr == 0) {
        #pragma unroll
        for (int r = 0; r < 4; r++) {
            pm_g[pidx * 64 + w16 + quad * 4 + r] = mrow[r];
            pl_g[pidx * 64 + w16 + quad * 4 + r] = lrow[r];
        }
    }
}

// ---------------------------------------------------------------- merge partials -> ctx as split bf16
__global__ void attn_merge(const float* __restrict__ po, const float* __restrict__ pm,
                           const float* __restrict__ pl,
                           __hip_bfloat16* __restrict__ ch, __hip_bfloat16* __restrict__ cl) {
    int qt = blockIdx.x, h = blockIdx.y, b = blockIdx.z;
    int bh = b * 16 + h;
    int nc = (qt + 4) >> 2;
    int base = (bh * 16 + qt) * 4;
    int tid = threadIdx.x;
    int r  = tid >> 2;
    int d0 = (tid & 3) * 16;
    float mstar = -1e30f;
    for (int c = 0; c < nc; c++) mstar = fmaxf(mstar, pm[(base + c) * 64 + r]);
    float a[4];
    float lsum = 0.f;
    for (int c = 0; c < nc; c++) {
        a[c] = __expf(pm[(base + c) * 64 + r] - mstar);
        lsum += a[c] * pl[(base + c) * 64 + r];
    }
    float inv = 1.f / lsum;
    size_t crow = (size_t)(b * SEQ + qt * 64 + r) * HS + h * HDIM;
    for (int dd = 0; dd < 16; dd += 4) {
        float4 acc = make_float4(0.f, 0.f, 0.f, 0.f);
        for (int c = 0; c < nc; c++) {
            float4 v = *(const float4*)(po + (size_t)(base + c) * 4096 + r * 64 + d0 + dd);
            acc.x += a[c] * v.x; acc.y += a[c] * v.y;
            acc.z += a[c] * v.z; acc.w += a[c] * v.w;
        }
        float vs[4] = {acc.x * inv, acc.y * inv, acc.z * inv, acc.w * inv};
        #pragma unroll
        for (int j = 0; j < 4; j++) {
            __hip_bfloat16 hi = __float2bfloat16(vs[j]);
            ch[crow + d0 + dd + j] = hi;
            cl[crow + d0 + dd + j] = __float2bfloat16(vs[j] - __bfloat162float(hi));
        }
    }
}

// ---------------------------------------------------------------- router (per-token top2)
__global__ void router_kernel(const float* __restrict__ hn, const float* __restrict__ rw,
                              int* __restrict__ cnt, int* __restrict__ topEk,
                              float* __restrict__ topW) {
    int t = blockIdx.x;
    int lane = threadIdx.x;
    float acc[NEXP];
    #pragma unroll
    for (int e = 0; e < NEXP; e++) acc[e] = 0.f;
    const float* row = hn + (size_t)t * HS;
    for (int kk = lane; kk < HS; kk += 64) {
        float xv = row[kk];
        const float* r = rw + (size_t)kk * NEXP;
        #pragma unroll
        for (int e = 0; e < NEXP; e++) acc[e] += xv * r[e];
    }
    #pragma unroll
    for (int e = 0; e < NEXP; e++)
        for (int off = 32; off > 0; off >>= 1) acc[e] += __shfl_down(acc[e], off);
    if (lane == 0) {
        float mx = acc[0];
        #pragma unroll
        for (int e = 1; e < NEXP; e++) mx = fmaxf(mx, acc[e]);
        float p[NEXP]; float s = 0.f;
        #pragma unroll
        for (int e = 0; e < NEXP; e++) { p[e] = __expf(acc[e] - mx); s += p[e]; }
        int i0 = 0;
        #pragma unroll
        for (int e = 1; e < NEXP; e++) if (p[e] > p[i0]) i0 = e;
        int i1 = (i0 == 0) ? 1 : 0;
        #pragma unroll
        for (int e = 0; e < NEXP; e++) if (e != i0 && p[e] > p[i1]) i1 = e;
        float v0 = p[i0], v1 = p[i1], sn = v0 + v1;
        topEk[2 * t]     = i0; topW[2 * t]     = v0 / sn;
        topEk[2 * t + 1] = i1; topW[2 * t + 1] = v1 / sn;
        atomicAdd(&cnt[i0], 1);
        atomicAdd(&cnt[i1], 1);
    }
}

// ---------------------------------------------------------------- offsets + block table
__global__ void offsets_kernel(const int* __restrict__ cnt, int* __restrict__ off,
                               int* __restrict__ blk_e, int* __restrict__ blk_r) {
    if (threadIdx.x == 0) {
        int o = 0, n = 0;
        for (int e = 0; e < NEXP; e++) {
            off[e] = o;
            for (int bm = 0; bm < cnt[e]; bm += 128) { blk_e[n] = e; blk_r[n] = bm; n++; }
            o += cnt[e];
        }
        for (; n < MAXBLK; n++) { blk_e[n] = -1; blk_r[n] = 0; }
    }
}

__global__ void scatter_kernel(const int* __restrict__ topEk, int* __restrict__ fill,
                               const int* __restrict__ off, const float* __restrict__ topW,
                               int* __restrict__ tok_list, float* __restrict__ wA) {
    int idx = blockIdx.x * 256 + threadIdx.x;
    int e = topEk[idx];
    int slot = atomicAdd(&fill[e], 1);
    int gidx = off[e] + slot;
    tok_list[gidx] = idx >> 1;
    wA[gidx] = topW[idx];
}

// ---------------------------------------------------------------- MoE up-proj, 128x128 tile, dbuf DMA
__global__ __launch_bounds__(256) void moe_up_mfma(const __hip_bfloat16* __restrict__ Abf,
                                                   const __hip_bfloat16* __restrict__ B1T,
                                                   const __hip_bfloat16* __restrict__ B3T,
                                                   __hip_bfloat16* __restrict__ g,
                                                   const int* __restrict__ cnt,
                                                   const int* __restrict__ off,
                                                   const int* __restrict__ tok_list,
                                                   const int* __restrict__ blk_e,
                                                   const int* __restrict__ blk_r) {
    int e = blk_e[blockIdx.y];
    if (e < 0) return;
    int bm = blk_r[blockIdx.y];
    int ce = cnt[e], oe = off[e];
    int bn = blockIdx.x * 128;
    const __hip_bfloat16* b1 = B1T + (size_t)e * IS * HS;   // [IS][HS]
    const __hip_bfloat16* b3 = B3T + (size_t)e * IS * HS;

    __shared__ __align__(16) short As[2][128][32];    // 16 KB
    __shared__ __align__(16) short B1s[2][128][32];   // 16 KB
    __shared__ __align__(16) short B3s[2][128][32];   // 16 KB -> 48 KB

    int t = threadIdx.x;
    int wave = t >> 6, lane = t & 63;
    int wm = (wave & 1) * 64, wn = (wave >> 1) * 64;
    int fr = lane & 15, quad = lane >> 4;
    int rA = wave * 32;
    int srow = lane >> 2;
    int schunk = (lane & 3) ^ ((lane >> 3) & 3);
    int tokA0 = tok_list[oe + min(bm + rA + srow, ce - 1)];
    int tokA1 = tok_list[oe + min(bm + rA + 16 + srow, ce - 1)];
    const __hip_bfloat16* pA0 = Abf + (size_t)tokA0 * HS + schunk * 8;
    const __hip_bfloat16* pA1 = Abf + (size_t)tokA1 * HS + schunk * 8;
    const __hip_bfloat16* pB1_0 = b1 + (size_t)(bn + rA + srow) * HS + schunk * 8;
    const __hip_bfloat16* pB1_1 = pB1_0 + (size_t)16 * HS;
    const __hip_bfloat16* pB3_0 = b3 + (size_t)(bn + rA + srow) * HS + schunk * 8;
    const __hip_bfloat16* pB3_1 = pB3_0 + (size_t)16 * HS;
    int ca = (quad ^ ((fr >> 1) & 3)) * 8;

    ldsdma16(&As[0][rA][0],       pA0);
    ldsdma16(&As[0][rA + 16][0],  pA1);
    ldsdma16(&B1s[0][rA][0],      pB1_0);
    ldsdma16(&B1s[0][rA + 16][0], pB1_1);
    ldsdma16(&B3s[0][rA][0],      pB3_0);
    ldsdma16(&B3s[0][rA + 16][0], pB3_1);

    f32x4 acc1[4][4] = {};
    f32x4 acc3[4][4] = {};
    const int NIT = HS >> 5;
    for (int it = 0; it < NIT; it++) {
        int cur = it & 1;
        __syncthreads();
        if (it + 1 < NIT) {
            int k1 = (it + 1) << 5;
            int nxt = cur ^ 1;
            ldsdma16(&As[nxt][rA][0],       pA0 + k1);
            ldsdma16(&As[nxt][rA + 16][0],  pA1 + k1);
            ldsdma16(&B1s[nxt][rA][0],      pB1_0 + k1);
            ldsdma16(&B1s[nxt][rA + 16][0], pB1_1 + k1);
            ldsdma16(&B3s[nxt][rA][0],      pB3_0 + k1);
            ldsdma16(&B3s[nxt][rA + 16][0], pB3_1 + k1);
        }
        bf16x8 a[4], f1[4], f3[4];
        #pragma unroll
        for (int i = 0; i < 4; i++) a[i] = *(const bf16x8*)&As[cur][wm + i * 16 + fr][ca];
        #pragma unroll
        for (int i = 0; i < 4; i++) {
            f1[i] = *(const bf16x8*)&B1s[cur][wn + i * 16 + fr][ca];
            f3[i] = *(const bf16x8*)&B3s[cur][wn + i * 16 + fr][ca];
        }
        #pragma unroll
        for (int mi = 0; mi < 4; mi++)
            #pragma unroll
            for (int ni = 0; ni < 4; ni++) {
                acc1[mi][ni] = __builtin_amdgcn_mfma_f32_16x16x32_bf16(a[mi], f1[ni], acc1[mi][ni], 0, 0, 0);
                acc3[mi][ni] = __builtin_amdgcn_mfma_f32_16x16x32_bf16(a[mi], f3[ni], acc3[mi][ni], 0, 0, 0);
            }
    }
    int rq = quad * 4;
    #pragma unroll
    for (int mi = 0; mi < 4; mi++) {
        #pragma unroll
        for (int r = 0; r < 4; r++) {
            int slot = bm + wm + mi * 16 + rq + r;
            if (slot < ce) {
                size_t rowo = (size_t)(oe + slot) * IS + bn + wn;
                #pragma unroll
                for (int ni = 0; ni < 4; ni++) {
                    float x1 = acc1[mi][ni][r];
                    float x3 = acc3[mi][ni][r];
                    float sv = (x1 / (1.f + __expf(-x1))) * x3;
                    g[rowo + ni * 16 + fr] = __float2bfloat16(sv);
                }
            }
        }
    }
}

// ---------------------------------------------------------------- MoE down-proj, 128x128 tile, split-K=2, dbuf DMA
__global__ __launch_bounds__(256) void moe_down_mfma(const __hip_bfloat16* __restrict__ g,
                                                     const __hip_bfloat16* __restrict__ B2T,
                                                     float* __restrict__ out,
                                                     const int* __restrict__ cnt,
                                                     const int* __restrict__ off,
                                                     const int* __restrict__ tok_list,
                                                     const float* __restrict__ wA,
                                                     const int* __restrict__ blk_e,
                                                     const int* __restrict__ blk_r) {
    int e = blk_e[blockIdx.y];
    if (e < 0) return;
    int bm = blk_r[blockIdx.y];
    int ce = cnt[e], oe = off[e];
    int bn = blockIdx.x * 128;
    int kz = blockIdx.z * (IS / 2);           // split-K half
    const __hip_bfloat16* b2 = B2T + (size_t)e * HS * IS;   // [HS][IS]

    __shared__ __align__(16) short As[2][128][32];   // 16 KB
    __shared__ __align__(16) short Bs[2][128][32];   // 16 KB -> 32 KB

    int t = threadIdx.x;
    int wave = t >> 6, lane = t & 63;
    int wm = (wave & 1) * 64, wn = (wave >> 1) * 64;
    int fr = lane & 15, quad = lane >> 4;
    int rA = wave * 32;
    int srow = lane >> 2;
    int schunk = (lane & 3) ^ ((lane >> 3) & 3);
    int ga0 = oe + min(bm + rA + srow, ce - 1);
    int ga1 = oe + min(bm + rA + 16 + srow, ce - 1);
    const __hip_bfloat16* pA0 = g + (size_t)ga0 * IS + kz + schunk * 8;
    const __hip_bfloat16* pA1 = g + (size_t)ga1 * IS + kz + schunk * 8;
    const __hip_bfloat16* pB0 = b2 + (size_t)(bn + rA + srow) * IS + kz + schunk * 8;
    const __hip_bfloat16* pB1 = pB0 + (size_t)16 * IS;
    int ca = (quad ^ ((fr >> 1) & 3)) * 8;

    ldsdma16(&As[0][rA][0],      pA0);
    ldsdma16(&As[0][rA + 16][0], pA1);
    ldsdma16(&Bs[0][rA][0],      pB0);
    ldsdma16(&Bs[0][rA + 16][0], pB1);

    f32x4 acc[4][4] = {};
    const int NIT = (IS / 2) >> 5;
    for (int it = 0; it < NIT; it++) {
        int cur = it & 1;
        __syncthreads();
        if (it + 1 < NIT) {
            int k1 = (it + 1) << 5;
            int nxt = cur ^ 1;
            ldsdma16(&As[nxt][rA][0],      pA0 + k1);
            ldsdma16(&As[nxt][rA + 16][0], pA1 + k1);
            ldsdma16(&Bs[nxt][rA][0],      pB0 + k1);
            ldsdma16(&Bs[nxt][rA + 16][0], pB1 + k1);
        }
        bf16x8 a[4], f[4];
        #pragma unroll
        for (int i = 0; i < 4; i++) a[i] = *(const bf16x8*)&As[cur][wm + i * 16 + fr][ca];
        #pragma unroll
        for (int i = 0; i < 4; i++) f[i] = *(const bf16x8*)&Bs[cur][wn + i * 16 + fr][ca];
        #pragma unroll
        for (int mi = 0; mi < 4; mi++)
            #pragma unroll
            for (int ni = 0; ni < 4; ni++)
                acc[mi][ni] = __builtin_amdgcn_mfma_f32_16x16x32_bf16(a[mi], f[ni], acc[mi][ni], 0, 0, 0);
    }
    int rq = quad * 4;
    #pragma unroll
    for (int mi = 0; mi < 4; mi++) {
        #pragma unroll
        for (int r = 0; r < 4; r++) {
            int slot = bm + wm + mi * 16 + rq + r;
            if (slot < ce) {
                int gidx = oe + slot;
                int tok = tok_list[gidx];
                float wgt = wA[gidx];
                size_t rowo = (size_t)tok * HS + bn + wn;
                #pragma unroll
                for (int ni = 0; ni < 4; ni++)
                    atomicAdd(out + rowo + ni * 16 + fr, wgt * acc[mi][ni][r]);
            }
        }
    }
}

// ---------------------------------------------------------------- launch
extern "C" void kernel_launch(void* const* d_in, const int* in_sizes, int n_in,
                              void* d_out, int out_size, void* d_ws, size_t ws_size,
                              hipStream_t stream) {
    const float* x   = (const float*)d_in[0];
    const float* anw = (const float*)d_in[1];
    const float* fnw = (const float*)d_in[2];
    const float* wq  = (const float*)d_in[3];
    const float* wk  = (const float*)d_in[4];
    const float* wv  = (const float*)d_in[5];
    const float* wo  = (const float*)d_in[6];
    const float* rw  = (const float*)d_in[7];
    const float* w1  = (const float*)d_in[8];
    const float* w3  = (const float*)d_in[9];
    const float* w2  = (const float*)d_in[10];
    const float* fc  = (const float*)d_in[11];
    float* out = (float*)d_out;

    char* ws = (char*)d_ws;
    const size_t MB = 1024 * 1024;
    __hip_bfloat16* xn_h  = (__hip_bfloat16*)(ws + 0 * MB);
    __hip_bfloat16* xn_l  = (__hip_bfloat16*)(ws + 4 * MB);
    float*          qkv   = (float*)(ws + 8 * MB);
    __hip_bfloat16* WqT_h = (__hip_bfloat16*)(ws + 32 * MB);
    __hip_bfloat16* WqT_l = (__hip_bfloat16*)(ws + 38 * MB);
    __hip_bfloat16* woT_h = (__hip_bfloat16*)(ws + 44 * MB);
    __hip_bfloat16* woT_l = (__hip_bfloat16*)(ws + 46 * MB);
    float*          po    = (float*)(ws + 48 * MB);
    float*          pm    = (float*)(ws + 82 * MB);
    float*          plb   = (float*)(ws + 83 * MB);
    __hip_bfloat16* ctx_h = (__hip_bfloat16*)(ws + 84 * MB);
    __hip_bfloat16* ctx_l = (__hip_bfloat16*)(ws + 88 * MB);
    __hip_bfloat16* qhb   = (__hip_bfloat16*)(ws + 92 * MB);
    __hip_bfloat16* qlb   = (__hip_bfloat16*)(ws + 96 * MB);
    __hip_bfloat16* khb   = (__hip_bfloat16*)(ws + 100 * MB);
    __hip_bfloat16* klb   = (__hip_bfloat16*)(ws + 104 * MB);
    __hip_bfloat16* vhb   = (__hip_bfloat16*)(ws + 108 * MB);
    __hip_bfloat16* vlb   = (__hip_bfloat16*)(ws + 112 * MB);
    float*          hn    = (float*)(ws + 0 * MB);
    __hip_bfloat16* hn_bf = (__hip_bfloat16*)(ws + 8 * MB);
    __hip_bfloat16* w1T   = (__hip_bfloat16*)(ws + 12 * MB);
    __hip_bfloat16* w3T   = (__hip_bfloat16*)(ws + 44 * MB);
    __hip_bfloat16* w2T   = (__hip_bfloat16*)(ws + 76 * MB);
    __hip_bfloat16* gact  = (__hip_bfloat16*)(ws + 108 * MB);
    int* ibase    = (int*)(ws + 124 * MB);
    int* cnt      = ibase;                 // 8
    int* fill     = ibase + 8;             // 8
    int* off      = ibase + 16;            // 8
    int* blk_e    = ibase + 24;            // 40
    int* blk_r    = ibase + 64;            // 40
    int* topEk    = ibase + 128;           // 4096
    int* tok_list = ibase + 128 + NASSIGN; // 4096
    float* topW   = (float*)(ibase + 128 + 2 * NASSIGN);
    float* wA     = (float*)(ibase + 128 + 3 * NASSIGN);

    // ---- attention half ----
    transpose_split4<<<dim3(HS / 64, HS / 64, 4), 256, 0, stream>>>(
        wq, wk, wv, wo, WqT_h, WqT_l, woT_h, woT_l);
    rmsnorm_split<<<NTOK, 256, 0, stream>>>(x, anw, xn_h, xn_l);

    gemm_bf16x3<<<dim3(QKVW / 64, NTOK / 128), 256, 0, stream>>>(
        xn_h, xn_l, WqT_h, WqT_l, nullptr, qkv, NTOK, QKVW, HS);
    rope_convert<<<NTOK, 256, 0, stream>>>(qkv, fc, qhb, qlb, khb, klb, vhb, vlb);

    attn_partial<<<dim3(4, 16, 32), 256, 0, stream>>>(qhb, qlb, khb, klb, vhb, vlb, po, pm, plb);
    attn_merge<<<dim3(16, 16, 2), 256, 0, stream>>>(po, pm, plb, ctx_h, ctx_l);

    gemm_bf16x3<<<dim3(HS / 64, NTOK / 128), 256, 0, stream>>>(
        ctx_h, ctx_l, woT_h, woT_l, x, out, NTOK, HS, HS);   // out = h = x + ctx@wo

    // ---- MoE half (routed top-2, bf16 MFMA experts) ----
    rmsnorm_dual<<<NTOK, 256, 0, stream>>>(out, fnw, hn, hn_bf);
    transpose_b64<<<dim3(IS / 64, HS / 64, NEXP), 256, 0, stream>>>(w1, w1T, HS, IS);
    transpose_b64<<<dim3(IS / 64, HS / 64, NEXP), 256, 0, stream>>>(w3, w3T, HS, IS);
    transpose_b64<<<dim3(HS / 64, IS / 64, NEXP), 256, 0, stream>>>(w2, w2T, IS, HS);

    hipMemsetAsync(cnt, 0, 16 * sizeof(int), stream);   // cnt + fill
    router_kernel<<<NTOK, 64, 0, stream>>>(hn, rw, cnt, topEk, topW);
    offsets_kernel<<<1, 64, 0, stream>>>(cnt, off, blk_e, blk_r);
    scatter_kernel<<<NASSIGN / 256, 256, 0, stream>>>(topEk, fill, off, topW, tok_list, wA);

    moe_up_mfma<<<dim3(IS / 128, MAXBLK), 256, 0, stream>>>(
        hn_bf, w1T, w3T, gact, cnt, off, tok_list, blk_e, blk_r);
    moe_down_mfma<<<dim3(HS / 128, MAXBLK, 2), 256, 0, stream>>>(
        gact, w2T, out, cnt, off, tok_list, wA, blk_e, blk_r);
}

// Round 3
// 626.020 us; speedup vs baseline: 1.0265x; 1.0265x over previous
//
#include <hip/hip_runtime.h>
#include <hip/hip_bf16.h>
#include <math.h>

#define HS 1024      // hidden size
#define IS 2048      // intermediate size
#define NHEAD 16
#define HDIM 64
#define NEXP 8
#define BATCH 2
#define SEQ 1024
#define NTOK (BATCH*SEQ)     // 2048 tokens
#define NASSIGN (NTOK*2)     // 4096 (token, expert) assignments
#define QKVW 3072            // fused qkv row width
#define PAD 72               // LDS row stride for attn (bf16 elems)
#define MAXBLK 40            // max 128-row blocks over all experts

typedef short bf16x8 __attribute__((ext_vector_type(8)));
typedef float f32x4  __attribute__((ext_vector_type(4)));
typedef unsigned short u16x8 __attribute__((ext_vector_type(8)));
typedef unsigned short u16x4 __attribute__((ext_vector_type(4)));

// async global->LDS, 16B per lane; lds dest = base + lane*16 (wave-uniform base)
__device__ __forceinline__ void ldsdma16(void* lds, const void* gp) {
    __builtin_amdgcn_global_load_lds(
        (const __attribute__((address_space(1))) void*)gp,
        (__attribute__((address_space(3))) void*)lds, 16, 0, 0);
}

// ---------------------------------------------------------------- rmsnorm -> split bf16 (hi+lo)
__global__ void rmsnorm_split(const float* __restrict__ x, const float* __restrict__ w,
                              __hip_bfloat16* __restrict__ oh, __hip_bfloat16* __restrict__ ol) {
    int t = blockIdx.x;
    int tid = threadIdx.x;
    const float* row = x + (size_t)t * HS;
    float4 v4 = *(const float4*)(row + tid * 4);
    float ss = v4.x * v4.x + v4.y * v4.y + v4.z * v4.z + v4.w * v4.w;
    for (int off = 32; off > 0; off >>= 1) ss += __shfl_down(ss, off);
    __shared__ float red[4];
    if ((tid & 63) == 0) red[tid >> 6] = ss;
    __syncthreads();
    float tot = red[0] + red[1] + red[2] + red[3];
    float rr = rsqrtf(tot / (float)HS + 1e-6f);
    float4 w4 = *(const float4*)(w + tid * 4);
    float vals[4] = {w4.x * v4.x * rr, w4.y * v4.y * rr, w4.z * v4.z * rr, w4.w * v4.w * rr};
    u16x4 h4, l4;
    #pragma unroll
    for (int j = 0; j < 4; j++) {
        __hip_bfloat16 hi = __float2bfloat16(vals[j]);
        __hip_bfloat16 lo = __float2bfloat16(vals[j] - __bfloat162float(hi));
        h4[j] = *(unsigned short*)&hi;
        l4[j] = *(unsigned short*)&lo;
    }
    *(u16x4*)&oh[(size_t)t * HS + tid * 4] = h4;
    *(u16x4*)&ol[(size_t)t * HS + tid * 4] = l4;
}

// ---------------------------------------------------------------- rmsnorm dual (fp32 + bf16)
__global__ void rmsnorm_dual(const float* __restrict__ x, const float* __restrict__ w,
                             float* __restrict__ outf, __hip_bfloat16* __restrict__ outb) {
    int t = blockIdx.x;
    int tid = threadIdx.x;
    const float* row = x + (size_t)t * HS;
    float4 v4 = *(const float4*)(row + tid * 4);
    float ss = v4.x * v4.x + v4.y * v4.y + v4.z * v4.z + v4.w * v4.w;
    for (int off = 32; off > 0; off >>= 1) ss += __shfl_down(ss, off);
    __shared__ float red[4];
    if ((tid & 63) == 0) red[tid >> 6] = ss;
    __syncthreads();
    float tot = red[0] + red[1] + red[2] + red[3];
    float rr = rsqrtf(tot / (float)HS + 1e-6f);
    float4 w4 = *(const float4*)(w + tid * 4);
    float4 o4 = make_float4(w4.x * v4.x * rr, w4.y * v4.y * rr, w4.z * v4.z * rr, w4.w * v4.w * rr);
    *(float4*)&outf[(size_t)t * HS + tid * 4] = o4;
    float vals[4] = {o4.x, o4.y, o4.z, o4.w};
    u16x4 b4;
    #pragma unroll
    for (int j = 0; j < 4; j++) {
        __hip_bfloat16 hi = __float2bfloat16(vals[j]);
        b4[j] = *(unsigned short*)&hi;
    }
    *(u16x4*)&outb[(size_t)t * HS + tid * 4] = b4;
}

// ---------------------------------------------------------------- fused 4-way transpose fp32 [1024][1024] -> split bf16 [C][R]
__global__ __launch_bounds__(256) void transpose_split4(
        const float* __restrict__ wq, const float* __restrict__ wk,
        const float* __restrict__ wv, const float* __restrict__ wo,
        __hip_bfloat16* __restrict__ qkvh, __hip_bfloat16* __restrict__ qkvl,
        __hip_bfloat16* __restrict__ oh, __hip_bfloat16* __restrict__ ol) {
    int z = blockIdx.z;
    const float* src = (z == 0) ? wq : (z == 1) ? wk : (z == 2) ? wv : wo;
    __hip_bfloat16* dh = (z < 3) ? qkvh : oh;
    __hip_bfloat16* dl = (z < 3) ? qkvl : ol;
    int rowOff = (z < 3) ? z * HS : 0;
    const int R = HS, C = HS;
    __shared__ float tile[64][65];
    int c0 = blockIdx.x * 64, r0 = blockIdx.y * 64;
    int tx = threadIdx.x & 15, ty = threadIdx.x >> 4;
    #pragma unroll
    for (int p = 0; p < 4; p++) {
        int r = ty + p * 16;
        float4 v = *(const float4*)(src + (size_t)(r0 + r) * C + c0 + tx * 4);
        tile[r][tx * 4 + 0] = v.x; tile[r][tx * 4 + 1] = v.y;
        tile[r][tx * 4 + 2] = v.z; tile[r][tx * 4 + 3] = v.w;
    }
    __syncthreads();
    int cc0 = threadIdx.x >> 3, rr = (threadIdx.x & 7) * 8;
    #pragma unroll
    for (int p = 0; p < 2; p++) {
        int cc = cc0 + p * 32;
        u16x8 h8, l8;
        #pragma unroll
        for (int j = 0; j < 8; j++) {
            float v = tile[rr + j][cc];
            __hip_bfloat16 hi = __float2bfloat16(v);
            __hip_bfloat16 lo = __float2bfloat16(v - __bfloat162float(hi));
            h8[j] = *(unsigned short*)&hi;
            l8[j] = *(unsigned short*)&lo;
        }
        size_t o = (size_t)(rowOff + c0 + cc) * R + r0 + rr;
        *(u16x8*)&dh[o] = h8;
        *(u16x8*)&dl[o] = l8;
    }
}

// ---------------------------------------------------------------- transpose fp32 [R][C] -> bf16 [C][R], per expert z, 64x64 tiles
__global__ __launch_bounds__(256) void transpose_b64(const float* __restrict__ in,
                                                     __hip_bfloat16* __restrict__ outp,
                                                     int R, int C) {
    int e = blockIdx.z;
    const float* src = in + (size_t)e * R * C;
    __hip_bfloat16* dst = outp + (size_t)e * R * C;
    __shared__ float tile[64][65];
    int c0 = blockIdx.x * 64, r0 = blockIdx.y * 64;
    int tx = threadIdx.x & 15, ty = threadIdx.x >> 4;
    #pragma unroll
    for (int p = 0; p < 4; p++) {
        int r = ty + p * 16;
        float4 v = *(const float4*)(src + (size_t)(r0 + r) * C + c0 + tx * 4);
        tile[r][tx * 4 + 0] = v.x; tile[r][tx * 4 + 1] = v.y;
        tile[r][tx * 4 + 2] = v.z; tile[r][tx * 4 + 3] = v.w;
    }
    __syncthreads();
    int cc0 = threadIdx.x >> 3, rr = (threadIdx.x & 7) * 8;
    #pragma unroll
    for (int p = 0; p < 2; p++) {
        int cc = cc0 + p * 32;
        u16x8 b8;
        #pragma unroll
        for (int j = 0; j < 8; j++) {
            __hip_bfloat16 hi = __float2bfloat16(tile[rr + j][cc]);
            b8[j] = *(unsigned short*)&hi;
        }
        *(u16x8*)&dst[(size_t)(c0 + cc) * R + r0 + rr] = b8;
    }
}

// ---------------------------------------------------------------- split-bf16 GEMM, 128x64 tile, dbuf DMA
// C[M][N] = (Ah+Al)[M][K] @ (Bh+Bl)[N][K]^T (+resid), via Ah@Bh + Ah@Bl + Al@Bh
__global__ __launch_bounds__(256) void gemm_bf16x3(const __hip_bfloat16* __restrict__ Ah,
                                                   const __hip_bfloat16* __restrict__ Al,
                                                   const __hip_bfloat16* __restrict__ Bh,
                                                   const __hip_bfloat16* __restrict__ Bl,
                                                   const float* __restrict__ resid,
                                                   float* __restrict__ C,
                                                   int M, int N, int K) {
    __shared__ __align__(16) short Ahs[2][128][32];   // 16 KB
    __shared__ __align__(16) short Als[2][128][32];   // 16 KB
    __shared__ __align__(16) short Bhs[2][64][32];    // 8 KB
    __shared__ __align__(16) short Bls[2][64][32];    // 8 KB -> 48 KB total
    int bm = blockIdx.y * 128, bn = blockIdx.x * 64;
    int t = threadIdx.x;
    int wave = t >> 6, lane = t & 63;
    int wm = (wave & 1) * 64, wn = (wave >> 1) * 32;
    int fr = lane & 15, quad = lane >> 4;
    int rA = wave * 32;            // A rows staged by this wave
    int rB = wave * 16;            // B rows staged by this wave
    int srow = lane >> 2;
    int schunk = (lane & 3) ^ ((lane >> 3) & 3);   // xor-swizzled 16B chunk
    const __hip_bfloat16* pAh0 = Ah + (size_t)(bm + rA + srow) * K + schunk * 8;
    const __hip_bfloat16* pAh1 = pAh0 + (size_t)16 * K;
    const __hip_bfloat16* pAl0 = Al + (size_t)(bm + rA + srow) * K + schunk * 8;
    const __hip_bfloat16* pAl1 = pAl0 + (size_t)16 * K;
    const __hip_bfloat16* pBh  = Bh + (size_t)(bn + rB + srow) * K + schunk * 8;
    const __hip_bfloat16* pBl  = Bl + (size_t)(bn + rB + srow) * K + schunk * 8;
    int ca = (quad ^ ((fr >> 1) & 3)) * 8;         // swizzled frag col (shorts)

    ldsdma16(&Ahs[0][rA][0],      pAh0);
    ldsdma16(&Ahs[0][rA + 16][0], pAh1);
    ldsdma16(&Als[0][rA][0],      pAl0);
    ldsdma16(&Als[0][rA + 16][0], pAl1);
    ldsdma16(&Bhs[0][rB][0],      pBh);
    ldsdma16(&Bls[0][rB][0],      pBl);

    f32x4 acc[4][2] = {};
    int NIT = K >> 5;
    for (int it = 0; it < NIT; it++) {
        int cur = it & 1;
        __syncthreads();
        if (it + 1 < NIT) {
            int k1 = (it + 1) << 5;
            int nxt = cur ^ 1;
            ldsdma16(&Ahs[nxt][rA][0],      pAh0 + k1);
            ldsdma16(&Ahs[nxt][rA + 16][0], pAh1 + k1);
            ldsdma16(&Als[nxt][rA][0],      pAl0 + k1);
            ldsdma16(&Als[nxt][rA + 16][0], pAl1 + k1);
            ldsdma16(&Bhs[nxt][rB][0],      pBh + k1);
            ldsdma16(&Bls[nxt][rB][0],      pBl + k1);
        }
        bf16x8 ah[4], bh[2], x[4];
        #pragma unroll
        for (int i = 0; i < 4; i++) ah[i] = *(const bf16x8*)&Ahs[cur][wm + i * 16 + fr][ca];
        #pragma unroll
        for (int i = 0; i < 2; i++) bh[i] = *(const bf16x8*)&Bhs[cur][wn + i * 16 + fr][ca];
        #pragma unroll
        for (int mi = 0; mi < 4; mi++)
            #pragma unroll
            for (int ni = 0; ni < 2; ni++)
                acc[mi][ni] = __builtin_amdgcn_mfma_f32_16x16x32_bf16(ah[mi], bh[ni], acc[mi][ni], 0, 0, 0);
        #pragma unroll
        for (int i = 0; i < 2; i++) x[i] = *(const bf16x8*)&Bls[cur][wn + i * 16 + fr][ca];
        #pragma unroll
        for (int mi = 0; mi < 4; mi++)
            #pragma unroll
            for (int ni = 0; ni < 2; ni++)
                acc[mi][ni] = __builtin_amdgcn_mfma_f32_16x16x32_bf16(ah[mi], x[ni], acc[mi][ni], 0, 0, 0);
        #pragma unroll
        for (int i = 0; i < 4; i++) x[i] = *(const bf16x8*)&Als[cur][wm + i * 16 + fr][ca];
        #pragma unroll
        for (int mi = 0; mi < 4; mi++)
            #pragma unroll
            for (int ni = 0; ni < 2; ni++)
                acc[mi][ni] = __builtin_amdgcn_mfma_f32_16x16x32_bf16(x[mi], bh[ni], acc[mi][ni], 0, 0, 0);
    }
    int rq = quad * 4;
    #pragma unroll
    for (int mi = 0; mi < 4; mi++) {
        #pragma unroll
        for (int r = 0; r < 4; r++) {
            size_t rowo = (size_t)(bm + wm + mi * 16 + rq + r) * N + bn + wn;
            #pragma unroll
            for (int ni = 0; ni < 2; ni++) {
                float v = acc[mi][ni][r];
                size_t o = rowo + ni * 16 + fr;
                if (resid) v += resid[o];
                C[o] = v;
            }
        }
    }
}

// ---------------------------------------------------------------- QKV GEMM with fused RoPE + split-bf16 epilogue
// Same main loop as gemm_bf16x3; epilogue applies RoPE (q,k) and writes split bf16
// directly to q/k/v hi+lo buffers. Block's 64-col stripe is entirely q, k, or v.
__global__ __launch_bounds__(256) void gemm_qkv_rope(const __hip_bfloat16* __restrict__ Ah,
                                                     const __hip_bfloat16* __restrict__ Al,
                                                     const __hip_bfloat16* __restrict__ Bh,
                                                     const __hip_bfloat16* __restrict__ Bl,
                                                     const float* __restrict__ fc,
                                                     __hip_bfloat16* __restrict__ qh, __hip_bfloat16* __restrict__ ql,
                                                     __hip_bfloat16* __restrict__ kh, __hip_bfloat16* __restrict__ kl,
                                                     __hip_bfloat16* __restrict__ vh, __hip_bfloat16* __restrict__ vl) {
    const int K = HS;
    __shared__ __align__(16) short Ahs[2][128][32];
    __shared__ __align__(16) short Als[2][128][32];
    __shared__ __align__(16) short Bhs[2][64][32];
    __shared__ __align__(16) short Bls[2][64][32];
    int bm = blockIdx.y * 128, bn = blockIdx.x * 64;
    int t = threadIdx.x;
    int wave = t >> 6, lane = t & 63;
    int wm = (wave & 1) * 64, wn = (wave >> 1) * 32;
    int fr = lane & 15, quad = lane >> 4;
    int rA = wave * 32;
    int rB = wave * 16;
    int srow = lane >> 2;
    int schunk = (lane & 3) ^ ((lane >> 3) & 3);
    const __hip_bfloat16* pAh0 = Ah + (size_t)(bm + rA + srow) * K + schunk * 8;
    const __hip_bfloat16* pAh1 = pAh0 + (size_t)16 * K;
    const __hip_bfloat16* pAl0 = Al + (size_t)(bm + rA + srow) * K + schunk * 8;
    const __hip_bfloat16* pAl1 = pAl0 + (size_t)16 * K;
    const __hip_bfloat16* pBh  = Bh + (size_t)(bn + rB + srow) * K + schunk * 8;
    const __hip_bfloat16* pBl  = Bl + (size_t)(bn + rB + srow) * K + schunk * 8;
    int ca = (quad ^ ((fr >> 1) & 3)) * 8;

    ldsdma16(&Ahs[0][rA][0],      pAh0);
    ldsdma16(&Ahs[0][rA + 16][0], pAh1);
    ldsdma16(&Als[0][rA][0],      pAl0);
    ldsdma16(&Als[0][rA + 16][0], pAl1);
    ldsdma16(&Bhs[0][rB][0],      pBh);
    ldsdma16(&Bls[0][rB][0],      pBl);

    f32x4 acc[4][2] = {};
    const int NIT = K >> 5;
    for (int it = 0; it < NIT; it++) {
        int cur = it & 1;
        __syncthreads();
        if (it + 1 < NIT) {
            int k1 = (it + 1) << 5;
            int nxt = cur ^ 1;
            ldsdma16(&Ahs[nxt][rA][0],      pAh0 + k1);
            ldsdma16(&Ahs[nxt][rA + 16][0], pAh1 + k1);
            ldsdma16(&Als[nxt][rA][0],      pAl0 + k1);
            ldsdma16(&Als[nxt][rA + 16][0], pAl1 + k1);
            ldsdma16(&Bhs[nxt][rB][0],      pBh + k1);
            ldsdma16(&Bls[nxt][rB][0],      pBl + k1);
        }
        bf16x8 ah[4], bh[2], x[4];
        #pragma unroll
        for (int i = 0; i < 4; i++) ah[i] = *(const bf16x8*)&Ahs[cur][wm + i * 16 + fr][ca];
        #pragma unroll
        for (int i = 0; i < 2; i++) bh[i] = *(const bf16x8*)&Bhs[cur][wn + i * 16 + fr][ca];
        #pragma unroll
        for (int mi = 0; mi < 4; mi++)
            #pragma unroll
            for (int ni = 0; ni < 2; ni++)
                acc[mi][ni] = __builtin_amdgcn_mfma_f32_16x16x32_bf16(ah[mi], bh[ni], acc[mi][ni], 0, 0, 0);
        #pragma unroll
        for (int i = 0; i < 2; i++) x[i] = *(const bf16x8*)&Bls[cur][wn + i * 16 + fr][ca];
        #pragma unroll
        for (int mi = 0; mi < 4; mi++)
            #pragma unroll
            for (int ni = 0; ni < 2; ni++)
                acc[mi][ni] = __builtin_amdgcn_mfma_f32_16x16x32_bf16(ah[mi], x[ni], acc[mi][ni], 0, 0, 0);
        #pragma unroll
        for (int i = 0; i < 4; i++) x[i] = *(const bf16x8*)&Als[cur][wm + i * 16 + fr][ca];
        #pragma unroll
        for (int mi = 0; mi < 4; mi++)
            #pragma unroll
            for (int ni = 0; ni < 2; ni++)
                acc[mi][ni] = __builtin_amdgcn_mfma_f32_16x16x32_bf16(x[mi], bh[ni], acc[mi][ni], 0, 0, 0);
    }
    // epilogue: block-uniform q/k/v selection (bn is a 64-aligned stripe)
    __hip_bfloat16 *dh, *dl;
    int cbase;
    bool dorope;
    if (bn < 1024)      { dh = qh; dl = ql; cbase = bn;        dorope = true;  }
    else if (bn < 2048) { dh = kh; dl = kl; cbase = bn - 1024; dorope = true;  }
    else                { dh = vh; dl = vl; cbase = bn - 2048; dorope = false; }
    float sgn = (fr & 1) ? 1.f : -1.f;
    int rq = quad * 4;
    #pragma unroll
    for (int mi = 0; mi < 4; mi++) {
        #pragma unroll
        for (int r = 0; r < 4; r++) {
            int trow = bm + wm + mi * 16 + rq + r;
            int s = trow & (SEQ - 1);
            size_t ob = (size_t)trow * HS + cbase;
            #pragma unroll
            for (int ni = 0; ni < 2; ni++) {
                float v = acc[mi][ni][r];
                int colh = wn + ni * 16 + fr;          // 0..63 within stripe = head pos
                float outv;
                if (dorope) {
                    float p = __shfl_xor(v, 1);
                    const float* fb = fc + (size_t)s * HDIM + (colh & ~1);
                    float cr = fb[0], ci = fb[1];
                    outv = v * cr + sgn * (p * ci);
                } else {
                    outv = v;
                }
                __hip_bfloat16 hi = __float2bfloat16(outv);
                __hip_bfloat16 lo = __float2bfloat16(outv - __bfloat162float(hi));
                dh[ob + colh] = hi;
                dl[ob + colh] = lo;
            }
        }
    }
}

// ---------------------------------------------------------------- split-K flash attention, MFMA split-bf16
__global__ __launch_bounds__(256) void attn_partial(
        const __hip_bfloat16* __restrict__ qh, const __hip_bfloat16* __restrict__ ql,
        const __hip_bfloat16* __restrict__ kh, const __hip_bfloat16* __restrict__ kl,
        const __hip_bfloat16* __restrict__ vh, const __hip_bfloat16* __restrict__ vl,
        float* __restrict__ po, float* __restrict__ pm_g, float* __restrict__ pl_g) {
    int c = blockIdx.x, qt = blockIdx.y;
    int nc = (qt + 4) >> 2;
    if (c >= nc) return;
    int bh = blockIdx.z;
    int b = bh >> 4, h = bh & 15;
    int t0 = c * 4, t1 = min(t0 + 4, qt + 1);
    int tid = threadIdx.x;
    int wave = tid >> 6, lane = tid & 63;
    int fr = lane & 15, quad = lane >> 4;
    int w16 = wave * 16;
    __shared__ __align__(16) short Qh[64][PAD], Ql[64][PAD];
    __shared__ __align__(16) short KPh[64][PAD], KPl[64][PAD];
    __shared__ __align__(16) short Vhs[64][PAD], Vls[64][PAD];
    size_t hoff = (size_t)h * HDIM;
    int sr = tid >> 2, sg = tid & 3;
    {
        const __hip_bfloat16* qp  = qh + (size_t)(b * SEQ + qt * 64 + sr) * HS + hoff;
        const __hip_bfloat16* qp2 = ql + (size_t)(b * SEQ + qt * 64 + sr) * HS + hoff;
        *(uint4*)&Qh[sr][sg * 8]       = *(const uint4*)(qp + sg * 8);
        *(uint4*)&Qh[sr][(sg + 4) * 8] = *(const uint4*)(qp + (sg + 4) * 8);
        *(uint4*)&Ql[sr][sg * 8]       = *(const uint4*)(qp2 + sg * 8);
        *(uint4*)&Ql[sr][(sg + 4) * 8] = *(const uint4*)(qp2 + (sg + 4) * 8);
    }
    f32x4 o[4] = {};
    float mrow[4], lrow[4];
    #pragma unroll
    for (int i = 0; i < 4; i++) { mrow[i] = -1e30f; lrow[i] = 0.f; }
    int key0 = (tid & 31) * 2, ds = tid >> 5;
    __syncthreads();

    for (int kt = t0; kt < t1; kt++) {
        int kbase = kt * 64;
        {
            const __hip_bfloat16* kp  = kh + (size_t)(b * SEQ + kbase + sr) * HS + hoff;
            const __hip_bfloat16* kp2 = kl + (size_t)(b * SEQ + kbase + sr) * HS + hoff;
            *(uint4*)&KPh[sr][sg * 8]       = *(const uint4*)(kp + sg * 8);
            *(uint4*)&KPh[sr][(sg + 4) * 8] = *(const uint4*)(kp + (sg + 4) * 8);
            *(uint4*)&KPl[sr][sg * 8]       = *(const uint4*)(kp2 + sg * 8);
            *(uint4*)&KPl[sr][(sg + 4) * 8] = *(const uint4*)(kp2 + (sg + 4) * 8);
        }
        {
            const __hip_bfloat16* v0 = vh + (size_t)(b * SEQ + kbase + key0) * HS + hoff + ds * 8;
            uint4 A = *(const uint4*)v0;
            uint4 Bv = *(const uint4*)(v0 + HS);
            const unsigned short* ap = (const unsigned short*)&A;
            const unsigned short* bp = (const unsigned short*)&Bv;
            #pragma unroll
            for (int j = 0; j < 8; j++)
                *(unsigned*)&Vhs[ds * 8 + j][key0] = (unsigned)ap[j] | ((unsigned)bp[j] << 16);
            const __hip_bfloat16* v2 = vl + (size_t)(b * SEQ + kbase + key0) * HS + hoff + ds * 8;
            uint4 A2 = *(const uint4*)v2;
            uint4 B2 = *(const uint4*)(v2 + HS);
            const unsigned short* ap2 = (const unsigned short*)&A2;
            const unsigned short* bp2 = (const unsigned short*)&B2;
            #pragma unroll
            for (int j = 0; j < 8; j++)
                *(unsigned*)&Vls[ds * 8 + j][key0] = (unsigned)ap2[j] | ((unsigned)bp2[j] << 16);
        }
        __syncthreads();

        f32x4 s[4] = {};
        #pragma unroll
        for (int ks = 0; ks < 2; ks++) {
            bf16x8 a_h = *(const bf16x8*)&Qh[w16 + fr][quad * 8 + ks * 32];
            bf16x8 a_l = *(const bf16x8*)&Ql[w16 + fr][quad * 8 + ks * 32];
            #pragma unroll
            for (int ni = 0; ni < 4; ni++) {
                bf16x8 b_h = *(const bf16x8*)&KPh[ni * 16 + fr][quad * 8 + ks * 32];
                bf16x8 b_l = *(const bf16x8*)&KPl[ni * 16 + fr][quad * 8 + ks * 32];
                s[ni] = __builtin_amdgcn_mfma_f32_16x16x32_bf16(a_h, b_h, s[ni], 0, 0, 0);
                s[ni] = __builtin_amdgcn_mfma_f32_16x16x32_bf16(a_h, b_l, s[ni], 0, 0, 0);
                s[ni] = __builtin_amdgcn_mfma_f32_16x16x32_bf16(a_l, b_h, s[ni], 0, 0, 0);
            }
        }
        int qg = qt * 64 + w16 + quad * 4;
        #pragma unroll
        for (int ni = 0; ni < 4; ni++) {
            int kg = kbase + ni * 16 + fr;
            #pragma unroll
            for (int r = 0; r < 4; r++)
                s[ni][r] = (kg > qg + r) ? -1e9f : s[ni][r] * 0.125f;
        }
        #pragma unroll
        for (int r = 0; r < 4; r++) {
            float mx = fmaxf(fmaxf(s[0][r], s[1][r]), fmaxf(s[2][r], s[3][r]));
            #pragma unroll
            for (int wd = 1; wd < 16; wd <<= 1) mx = fmaxf(mx, __shfl_xor(mx, wd));
            float nm = fmaxf(mrow[r], mx);
            float alpha = __expf(mrow[r] - nm);
            float rs = 0.f;
            #pragma unroll
            for (int ni = 0; ni < 4; ni++) { float e = __expf(s[ni][r] - nm); s[ni][r] = e; rs += e; }
            #pragma unroll
            for (int wd = 1; wd < 16; wd <<= 1) rs += __shfl_xor(rs, wd);
            lrow[r] = lrow[r] * alpha + rs;
            mrow[r] = nm;
            o[0][r] *= alpha; o[1][r] *= alpha; o[2][r] *= alpha; o[3][r] *= alpha;
        }
        __syncthreads();
        #pragma unroll
        for (int ni = 0; ni < 4; ni++)
            #pragma unroll
            for (int r = 0; r < 4; r++) {
                float pv = s[ni][r];
                __hip_bfloat16 hi = __float2bfloat16(pv);
                __hip_bfloat16 lo = __float2bfloat16(pv - __bfloat162float(hi));
                KPh[w16 + quad * 4 + r][ni * 16 + fr] = *(short*)&hi;
                KPl[w16 + quad * 4 + r][ni * 16 + fr] = *(short*)&lo;
            }
        #pragma unroll
        for (int ks = 0; ks < 2; ks++) {
            bf16x8 p_h = *(const bf16x8*)&KPh[w16 + fr][quad * 8 + ks * 32];
            bf16x8 p_l = *(const bf16x8*)&KPl[w16 + fr][quad * 8 + ks * 32];
            #pragma unroll
            for (int ni = 0; ni < 4; ni++) {
                bf16x8 v_h = *(const bf16x8*)&Vhs[ni * 16 + fr][quad * 8 + ks * 32];
                bf16x8 v_l = *(const bf16x8*)&Vls[ni * 16 + fr][quad * 8 + ks * 32];
                o[ni] = __builtin_amdgcn_mfma_f32_16x16x32_bf16(p_h, v_h, o[ni], 0, 0, 0);
                o[ni] = __builtin_amdgcn_mfma_f32_16x16x32_bf16(p_h, v_l, o[ni], 0, 0, 0);
                o[ni] = __builtin_amdgcn_mfma_f32_16x16x32_bf16(p_l, v_h, o[ni], 0, 0, 0);
            }
        }
        __syncthreads();
    }
    int pidx = (bh * 16 + qt) * 4 + c;
    float* pob = po + (size_t)pidx * 4096;
    #pragma unroll
    for (int ni = 0; ni < 4; ni++)
        #pragma unroll
        for (int r = 0; r < 4; r++)
            pob[(w16 + quad * 4 + r) * 64 + ni * 16 + fr] = o[ni][r];
    if (fr == 0) {
        #pragma unroll
        for (int r = 0; r < 4; r++) {
            pm_g[pidx * 64 + w16 + quad * 4 + r] = mrow[r];
            pl_g[pidx * 64 + w16 + quad * 4 + r] = lrow[r];
        }
    }
}

// ---------------------------------------------------------------- merge partials -> ctx as split bf16
__global__ void attn_merge(const float* __restrict__ po, const float* __restrict__ pm,
                           const float* __restrict__ pl,
                           __hip_bfloat16* __restrict__ ch, __hip_bfloat16* __restrict__ cl) {
    int qt = blockIdx.x, h = blockIdx.y, b = blockIdx.z;
    int bh = b * 16 + h;
    int nc = (qt + 4) >> 2;
    int base = (bh * 16 + qt) * 4;
    int tid = threadIdx.x;
    int r  = tid >> 2;
    int d0 = (tid & 3) * 16;
    float mstar = -1e30f;
    for (int c = 0; c < nc; c++) mstar = fmaxf(mstar, pm[(base + c) * 64 + r]);
    float a[4];
    float lsum = 0.f;
    for (int c = 0; c < nc; c++) {
        a[c] = __expf(pm[(base + c) * 64 + r] - mstar);
        lsum += a[c] * pl[(base + c) * 64 + r];
    }
    float inv = 1.f / lsum;
    size_t crow = (size_t)(b * SEQ + qt * 64 + r) * HS + h * HDIM;
    for (int dd = 0; dd < 16; dd += 4) {
        float4 acc = make_float4(0.f, 0.f, 0.f, 0.f);
        for (int c = 0; c < nc; c++) {
            float4 v = *(const float4*)(po + (size_t)(base + c) * 4096 + r * 64 + d0 + dd);
            acc.x += a[c] * v.x; acc.y += a[c] * v.y;
            acc.z += a[c] * v.z; acc.w += a[c] * v.w;
        }
        float vs[4] = {acc.x * inv, acc.y * inv, acc.z * inv, acc.w * inv};
        #pragma unroll
        for (int j = 0; j < 4; j++) {
            __hip_bfloat16 hi = __float2bfloat16(vs[j]);
            ch[crow + d0 + dd + j] = hi;
            cl[crow + d0 + dd + j] = __float2bfloat16(vs[j] - __bfloat162float(hi));
        }
    }
}

// ---------------------------------------------------------------- router (per-token top2)
__global__ void router_kernel(const float* __restrict__ hn, const float* __restrict__ rw,
                              int* __restrict__ cnt, int* __restrict__ topEk,
                              float* __restrict__ topW) {
    int t = blockIdx.x;
    int lane = threadIdx.x;
    float acc[NEXP];
    #pragma unroll
    for (int e = 0; e < NEXP; e++) acc[e] = 0.f;
    const float* row = hn + (size_t)t * HS;
    for (int kk = lane; kk < HS; kk += 64) {
        float xv = row[kk];
        const float* r = rw + (size_t)kk * NEXP;
        #pragma unroll
        for (int e = 0; e < NEXP; e++) acc[e] += xv * r[e];
    }
    #pragma unroll
    for (int e = 0; e < NEXP; e++)
        for (int off = 32; off > 0; off >>= 1) acc[e] += __shfl_down(acc[e], off);
    if (lane == 0) {
        float mx = acc[0];
        #pragma unroll
        for (int e = 1; e < NEXP; e++) mx = fmaxf(mx, acc[e]);
        float p[NEXP]; float s = 0.f;
        #pragma unroll
        for (int e = 0; e < NEXP; e++) { p[e] = __expf(acc[e] - mx); s += p[e]; }
        int i0 = 0;
        #pragma unroll
        for (int e = 1; e < NEXP; e++) if (p[e] > p[i0]) i0 = e;
        int i1 = (i0 == 0) ? 1 : 0;
        #pragma unroll
        for (int e = 0; e < NEXP; e++) if (e != i0 && p[e] > p[i1]) i1 = e;
        float v0 = p[i0], v1 = p[i1], sn = v0 + v1;
        topEk[2 * t]     = i0; topW[2 * t]     = v0 / sn;
        topEk[2 * t + 1] = i1; topW[2 * t + 1] = v1 / sn;
        atomicAdd(&cnt[i0], 1);
        atomicAdd(&cnt[i1], 1);
    }
}

// ---------------------------------------------------------------- offsets + block table
__global__ void offsets_kernel(const int* __restrict__ cnt, int* __restrict__ off,
                               int* __restrict__ blk_e, int* __restrict__ blk_r) {
    if (threadIdx.x == 0) {
        int o = 0, n = 0;
        for (int e = 0; e < NEXP; e++) {
            off[e] = o;
            for (int bm = 0; bm < cnt[e]; bm += 128) { blk_e[n] = e; blk_r[n] = bm; n++; }
            o += cnt[e];
        }
        for (; n < MAXBLK; n++) { blk_e[n] = -1; blk_r[n] = 0; }
    }
}

__global__ void scatter_kernel(const int* __restrict__ topEk, int* __restrict__ fill,
                               const int* __restrict__ off, const float* __restrict__ topW,
                               int* __restrict__ tok_list, float* __restrict__ wA) {
    int idx = blockIdx.x * 256 + threadIdx.x;
    int e = topEk[idx];
    int slot = atomicAdd(&fill[e], 1);
    int gidx = off[e] + slot;
    tok_list[gidx] = idx >> 1;
    wA[gidx] = topW[idx];
}

// ---------------------------------------------------------------- MoE up-proj, 128x64 tile, dbuf DMA
__global__ __launch_bounds__(256) void moe_up_mfma(const __hip_bfloat16* __restrict__ Abf,
                                                   const __hip_bfloat16* __restrict__ B1T,
                                                   const __hip_bfloat16* __restrict__ B3T,
                                                   __hip_bfloat16* __restrict__ g,
                                                   const int* __restrict__ cnt,
                                                   const int* __restrict__ off,
                                                   const int* __restrict__ tok_list,
                                                   const int* __restrict__ blk_e,
                                                   const int* __restrict__ blk_r) {
    int e = blk_e[blockIdx.y];
    if (e < 0) return;
    int bm = blk_r[blockIdx.y];
    int ce = cnt[e], oe = off[e];
    int bn = blockIdx.x * 64;
    const __hip_bfloat16* b1 = B1T + (size_t)e * IS * HS;   // [IS][HS]
    const __hip_bfloat16* b3 = B3T + (size_t)e * IS * HS;

    __shared__ __align__(16) short As[2][128][32];    // 16 KB
    __shared__ __align__(16) short B1s[2][64][32];    // 8 KB
    __shared__ __align__(16) short B3s[2][64][32];    // 8 KB -> 32 KB

    int t = threadIdx.x;
    int wave = t >> 6, lane = t & 63;
    int wm = (wave & 1) * 64, wn = (wave >> 1) * 32;
    int fr = lane & 15, quad = lane >> 4;
    int rA = wave * 32, rB = wave * 16;
    int srow = lane >> 2;
    int schunk = (lane & 3) ^ ((lane >> 3) & 3);
    int tokA0 = tok_list[oe + min(bm + rA + srow, ce - 1)];
    int tokA1 = tok_list[oe + min(bm + rA + 16 + srow, ce - 1)];
    const __hip_bfloat16* pA0 = Abf + (size_t)tokA0 * HS + schunk * 8;
    const __hip_bfloat16* pA1 = Abf + (size_t)tokA1 * HS + schunk * 8;
    const __hip_bfloat16* pB1 = b1 + (size_t)(bn + rB + srow) * HS + schunk * 8;
    const __hip_bfloat16* pB3 = b3 + (size_t)(bn + rB + srow) * HS + schunk * 8;
    int ca = (quad ^ ((fr >> 1) & 3)) * 8;

    ldsdma16(&As[0][rA][0],      pA0);
    ldsdma16(&As[0][rA + 16][0], pA1);
    ldsdma16(&B1s[0][rB][0],     pB1);
    ldsdma16(&B3s[0][rB][0],     pB3);

    f32x4 acc1[4][2] = {};
    f32x4 acc3[4][2] = {};
    const int NIT = HS >> 5;
    for (int it = 0; it < NIT; it++) {
        int cur = it & 1;
        __syncthreads();
        if (it + 1 < NIT) {
            int k1 = (it + 1) << 5;
            int nxt = cur ^ 1;
            ldsdma16(&As[nxt][rA][0],      pA0 + k1);
            ldsdma16(&As[nxt][rA + 16][0], pA1 + k1);
            ldsdma16(&B1s[nxt][rB][0],     pB1 + k1);
            ldsdma16(&B3s[nxt][rB][0],     pB3 + k1);
        }
        bf16x8 a[4], f1[2], f3[2];
        #pragma unroll
        for (int i = 0; i < 4; i++) a[i] = *(const bf16x8*)&As[cur][wm + i * 16 + fr][ca];
        #pragma unroll
        for (int i = 0; i < 2; i++) {
            f1[i] = *(const bf16x8*)&B1s[cur][wn + i * 16 + fr][ca];
            f3[i] = *(const bf16x8*)&B3s[cur][wn + i * 16 + fr][ca];
        }
        #pragma unroll
        for (int mi = 0; mi < 4; mi++)
            #pragma unroll
            for (int ni = 0; ni < 2; ni++) {
                acc1[mi][ni] = __builtin_amdgcn_mfma_f32_16x16x32_bf16(a[mi], f1[ni], acc1[mi][ni], 0, 0, 0);
                acc3[mi][ni] = __builtin_amdgcn_mfma_f32_16x16x32_bf16(a[mi], f3[ni], acc3[mi][ni], 0, 0, 0);
            }
    }
    int rq = quad * 4;
    #pragma unroll
    for (int mi = 0; mi < 4; mi++) {
        #pragma unroll
        for (int r = 0; r < 4; r++) {
            int slot = bm + wm + mi * 16 + rq + r;
            if (slot < ce) {
                size_t rowo = (size_t)(oe + slot) * IS + bn + wn;
                #pragma unroll
                for (int ni = 0; ni < 2; ni++) {
                    float x1 = acc1[mi][ni][r];
                    float x3 = acc3[mi][ni][r];
                    float sv = (x1 / (1.f + __expf(-x1))) * x3;
                    g[rowo + ni * 16 + fr] = __float2bfloat16(sv);
                }
            }
        }
    }
}

// ---------------------------------------------------------------- MoE down-proj, 128x64 tile, split-K=2, dbuf DMA
__global__ __launch_bounds__(256) void moe_down_mfma(const __hip_bfloat16* __restrict__ g,
                                                     const __hip_bfloat16* __restrict__ B2T,
                                                     float* __restrict__ out,
                                                     const int* __restrict__ cnt,
                                                     const int* __restrict__ off,
                                                     const int* __restrict__ tok_list,
                                                     const float* __restrict__ wA,
                                                     const int* __restrict__ blk_e,
                                                     const int* __restrict__ blk_r) {
    int e = blk_e[blockIdx.y];
    if (e < 0) return;
    int bm = blk_r[blockIdx.y];
    int ce = cnt[e], oe = off[e];
    int bn = blockIdx.x * 64;
    int kz = blockIdx.z * (IS / 2);           // split-K half
    const __hip_bfloat16* b2 = B2T + (size_t)e * HS * IS;   // [HS][IS]

    __shared__ __align__(16) short As[2][128][32];   // 16 KB
    __shared__ __align__(16) short Bs[2][64][32];    // 8 KB -> 24 KB

    int t = threadIdx.x;
    int wave = t >> 6, lane = t & 63;
    int wm = (wave & 1) * 64, wn = (wave >> 1) * 32;
    int fr = lane & 15, quad = lane >> 4;
    int rA = wave * 32, rB = wave * 16;
    int srow = lane >> 2;
    int schunk = (lane & 3) ^ ((lane >> 3) & 3);
    int ga0 = oe + min(bm + rA + srow, ce - 1);
    int ga1 = oe + min(bm + rA + 16 + srow, ce - 1);
    const __hip_bfloat16* pA0 = g + (size_t)ga0 * IS + kz + schunk * 8;
    const __hip_bfloat16* pA1 = g + (size_t)ga1 * IS + kz + schunk * 8;
    const __hip_bfloat16* pB  = b2 + (size_t)(bn + rB + srow) * IS + kz + schunk * 8;
    int ca = (quad ^ ((fr >> 1) & 3)) * 8;

    ldsdma16(&As[0][rA][0],      pA0);
    ldsdma16(&As[0][rA + 16][0], pA1);
    ldsdma16(&Bs[0][rB][0],      pB);

    f32x4 acc[4][2] = {};
    const int NIT = (IS / 2) >> 5;
    for (int it = 0; it < NIT; it++) {
        int cur = it & 1;
        __syncthreads();
        if (it + 1 < NIT) {
            int k1 = (it + 1) << 5;
            int nxt = cur ^ 1;
            ldsdma16(&As[nxt][rA][0],      pA0 + k1);
            ldsdma16(&As[nxt][rA + 16][0], pA1 + k1);
            ldsdma16(&Bs[nxt][rB][0],      pB + k1);
        }
        bf16x8 a[4], f[2];
        #pragma unroll
        for (int i = 0; i < 4; i++) a[i] = *(const bf16x8*)&As[cur][wm + i * 16 + fr][ca];
        #pragma unroll
        for (int i = 0; i < 2; i++) f[i] = *(const bf16x8*)&Bs[cur][wn + i * 16 + fr][ca];
        #pragma unroll
        for (int mi = 0; mi < 4; mi++)
            #pragma unroll
            for (int ni = 0; ni < 2; ni++)
                acc[mi][ni] = __builtin_amdgcn_mfma_f32_16x16x32_bf16(a[mi], f[ni], acc[mi][ni], 0, 0, 0);
    }
    int rq = quad * 4;
    #pragma unroll
    for (int mi = 0; mi < 4; mi++) {
        #pragma unroll
        for (int r = 0; r < 4; r++) {
            int slot = bm + wm + mi * 16 + rq + r;
            if (slot < ce) {
                int gidx = oe + slot;
                int tok = tok_list[gidx];
                float wgt = wA[gidx];
                size_t rowo = (size_t)tok * HS + bn + wn;
                #pragma unroll
                for (int ni = 0; ni < 2; ni++)
                    atomicAdd(out + rowo + ni * 16 + fr, wgt * acc[mi][ni][r]);
            }
        }
    }
}

// ---------------------------------------------------------------- launch
extern "C" void kernel_launch(void* const* d_in, const int* in_sizes, int n_in,
                              void* d_out, int out_size, void* d_ws, size_t ws_size,
                              hipStream_t stream) {
    const float* x   = (const float*)d_in[0];
    const float* anw = (const float*)d_in[1];
    const float* fnw = (const float*)d_in[2];
    const float* wq  = (const float*)d_in[3];
    const float* wk  = (const float*)d_in[4];
    const float* wv  = (const float*)d_in[5];
    const float* wo  = (const float*)d_in[6];
    const float* rw  = (const float*)d_in[7];
    const float* w1  = (const float*)d_in[8];
    const float* w3  = (const float*)d_in[9];
    const float* w2  = (const float*)d_in[10];
    const float* fc  = (const float*)d_in[11];
    float* out = (float*)d_out;

    char* ws = (char*)d_ws;
    const size_t MB = 1024 * 1024;
    __hip_bfloat16* xn_h  = (__hip_bfloat16*)(ws + 0 * MB);
    __hip_bfloat16* xn_l  = (__hip_bfloat16*)(ws + 4 * MB);
    __hip_bfloat16* WqT_h = (__hip_bfloat16*)(ws + 32 * MB);
    __hip_bfloat16* WqT_l = (__hip_bfloat16*)(ws + 38 * MB);
    __hip_bfloat16* woT_h = (__hip_bfloat16*)(ws + 44 * MB);
    __hip_bfloat16* woT_l = (__hip_bfloat16*)(ws + 46 * MB);
    float*          po    = (float*)(ws + 48 * MB);
    float*          pm    = (float*)(ws + 82 * MB);
    float*          plb   = (float*)(ws + 83 * MB);
    __hip_bfloat16* ctx_h = (__hip_bfloat16*)(ws + 84 * MB);
    __hip_bfloat16* ctx_l = (__hip_bfloat16*)(ws + 88 * MB);
    __hip_bfloat16* qhb   = (__hip_bfloat16*)(ws + 92 * MB);
    __hip_bfloat16* qlb   = (__hip_bfloat16*)(ws + 96 * MB);
    __hip_bfloat16* khb   = (__hip_bfloat16*)(ws + 100 * MB);
    __hip_bfloat16* klb   = (__hip_bfloat16*)(ws + 104 * MB);
    __hip_bfloat16* vhb   = (__hip_bfloat16*)(ws + 108 * MB);
    __hip_bfloat16* vlb   = (__hip_bfloat16*)(ws + 112 * MB);
    float*          hn    = (float*)(ws + 0 * MB);
    __hip_bfloat16* hn_bf = (__hip_bfloat16*)(ws + 8 * MB);
    __hip_bfloat16* w1T   = (__hip_bfloat16*)(ws + 12 * MB);
    __hip_bfloat16* w3T   = (__hip_bfloat16*)(ws + 44 * MB);
    __hip_bfloat16* w2T   = (__hip_bfloat16*)(ws + 76 * MB);
    __hip_bfloat16* gact  = (__hip_bfloat16*)(ws + 108 * MB);
    int* ibase    = (int*)(ws + 124 * MB);
    int* cnt      = ibase;                 // 8
    int* fill     = ibase + 8;             // 8
    int* off      = ibase + 16;            // 8
    int* blk_e    = ibase + 24;            // 40
    int* blk_r    = ibase + 64;            // 40
    int* topEk    = ibase + 128;           // 4096
    int* tok_list = ibase + 128 + NASSIGN; // 4096
    float* topW   = (float*)(ibase + 128 + 2 * NASSIGN);
    float* wA     = (float*)(ibase + 128 + 3 * NASSIGN);

    // ---- attention half ----
    transpose_split4<<<dim3(HS / 64, HS / 64, 4), 256, 0, stream>>>(
        wq, wk, wv, wo, WqT_h, WqT_l, woT_h, woT_l);
    rmsnorm_split<<<NTOK, 256, 0, stream>>>(x, anw, xn_h, xn_l);

    gemm_qkv_rope<<<dim3(QKVW / 64, NTOK / 128), 256, 0, stream>>>(
        xn_h, xn_l, WqT_h, WqT_l, fc, qhb, qlb, khb, klb, vhb, vlb);

    attn_partial<<<dim3(4, 16, 32), 256, 0, stream>>>(qhb, qlb, khb, klb, vhb, vlb, po, pm, plb);
    attn_merge<<<dim3(16, 16, 2), 256, 0, stream>>>(po, pm, plb, ctx_h, ctx_l);

    gemm_bf16x3<<<dim3(HS / 64, NTOK / 128), 256, 0, stream>>>(
        ctx_h, ctx_l, woT_h, woT_l, x, out, NTOK, HS, HS);   // out = h = x + ctx@wo

    // ---- MoE half (routed top-2, bf16 MFMA experts) ----
    rmsnorm_dual<<<NTOK, 256, 0, stream>>>(out, fnw, hn, hn_bf);
    transpose_b64<<<dim3(IS / 64, HS / 64, NEXP), 256, 0, stream>>>(w1, w1T, HS, IS);
    transpose_b64<<<dim3(IS / 64, HS / 64, NEXP), 256, 0, stream>>>(w3, w3T, HS, IS);
    transpose_b64<<<dim3(HS / 64, IS / 64, NEXP), 256, 0, stream>>>(w2, w2T, IS, HS);

    hipMemsetAsync(cnt, 0, 16 * sizeof(int), stream);   // cnt + fill
    router_kernel<<<NTOK, 64, 0, stream>>>(hn, rw, cnt, topEk, topW);
    offsets_kernel<<<1, 64, 0, stream>>>(cnt, off, blk_e, blk_r);
    scatter_kernel<<<NASSIGN / 256, 256, 0, stream>>>(topEk, fill, off, topW, tok_list, wA);

    moe_up_mfma<<<dim3(IS / 64, MAXBLK), 256, 0, stream>>>(
        hn_bf, w1T, w3T, gact, cnt, off, tok_list, blk_e, blk_r);
    moe_down_mfma<<<dim3(HS / 64, MAXBLK, 2), 256, 0, stream>>>(
        gact, w2T, out, cnt, off, tok_list, wA, blk_e, blk_r);
}

// Round 5
// 609.506 us; speedup vs baseline: 1.0543x; 1.0271x over previous
//
#include <hip/hip_runtime.h>
#include <hip/hip_bf16.h>
#include <math.h>

#define HS 1024      // hidden size
#define IS 2048      // intermediate size
#define NHEAD 16
#define HDIM 64
#define NEXP 8
#define BATCH 2
#define SEQ 1024
#define NTOK (BATCH*SEQ)     // 2048 tokens
#define NASSIGN (NTOK*2)     // 4096 (token, expert) assignments
#define QKVW 3072            // fused qkv row width
#define PAD 72               // LDS row stride for attn (bf16 elems)
#define MAXBLK 40            // max 128-row blocks over all experts

typedef short bf16x8 __attribute__((ext_vector_type(8)));
typedef float f32x4  __attribute__((ext_vector_type(4)));
typedef unsigned short u16x8 __attribute__((ext_vector_type(8)));
typedef unsigned short u16x4 __attribute__((ext_vector_type(4)));

// async global->LDS, 16B per lane; lds dest = base + lane*16 (wave-uniform base)
__device__ __forceinline__ void ldsdma16(void* lds, const void* gp) {
    __builtin_amdgcn_global_load_lds(
        (const __attribute__((address_space(1))) void*)gp,
        (__attribute__((address_space(3))) void*)lds, 16, 0, 0);
}

// ---------------------------------------------------------------- rmsnorm -> split bf16 (hi+lo)
__global__ void rmsnorm_split(const float* __restrict__ x, const float* __restrict__ w,
                              __hip_bfloat16* __restrict__ oh, __hip_bfloat16* __restrict__ ol) {
    int t = blockIdx.x;
    int tid = threadIdx.x;
    const float* row = x + (size_t)t * HS;
    float4 v4 = *(const float4*)(row + tid * 4);
    float ss = v4.x * v4.x + v4.y * v4.y + v4.z * v4.z + v4.w * v4.w;
    for (int off = 32; off > 0; off >>= 1) ss += __shfl_down(ss, off);
    __shared__ float red[4];
    if ((tid & 63) == 0) red[tid >> 6] = ss;
    __syncthreads();
    float tot = red[0] + red[1] + red[2] + red[3];
    float rr = rsqrtf(tot / (float)HS + 1e-6f);
    float4 w4 = *(const float4*)(w + tid * 4);
    float vals[4] = {w4.x * v4.x * rr, w4.y * v4.y * rr, w4.z * v4.z * rr, w4.w * v4.w * rr};
    u16x4 h4, l4;
    #pragma unroll
    for (int j = 0; j < 4; j++) {
        __hip_bfloat16 hi = __float2bfloat16(vals[j]);
        __hip_bfloat16 lo = __float2bfloat16(vals[j] - __bfloat162float(hi));
        h4[j] = *(unsigned short*)&hi;
        l4[j] = *(unsigned short*)&lo;
    }
    *(u16x4*)&oh[(size_t)t * HS + tid * 4] = h4;
    *(u16x4*)&ol[(size_t)t * HS + tid * 4] = l4;
}

// ---------------------------------------------------------------- fused rmsnorm (bf16 out) + router top-2
__global__ void rmsnorm_router(const float* __restrict__ x, const float* __restrict__ w,
                               const float* __restrict__ rw,
                               __hip_bfloat16* __restrict__ outb,
                               int* __restrict__ cnt, int* __restrict__ topEk,
                               float* __restrict__ topW) {
    int t = blockIdx.x;
    int tid = threadIdx.x;
    const float* row = x + (size_t)t * HS;
    float4 v4 = *(const float4*)(row + tid * 4);
    float ss = v4.x * v4.x + v4.y * v4.y + v4.z * v4.z + v4.w * v4.w;
    for (int off = 32; off > 0; off >>= 1) ss += __shfl_down(ss, off);
    __shared__ float red[4];
    __shared__ float lred[4][NEXP];
    if ((tid & 63) == 0) red[tid >> 6] = ss;
    __syncthreads();
    float tot = red[0] + red[1] + red[2] + red[3];
    float rr = rsqrtf(tot / (float)HS + 1e-6f);
    float4 w4 = *(const float4*)(w + tid * 4);
    float vals[4] = {w4.x * v4.x * rr, w4.y * v4.y * rr, w4.z * v4.z * rr, w4.w * v4.w * rr};
    u16x4 b4;
    #pragma unroll
    for (int j = 0; j < 4; j++) {
        __hip_bfloat16 hi = __float2bfloat16(vals[j]);
        b4[j] = *(unsigned short*)&hi;
    }
    *(u16x4*)&outb[(size_t)t * HS + tid * 4] = b4;
    // router logits: acc_e += x_norm[i] * rw[i][e]
    float acc[NEXP];
    #pragma unroll
    for (int e = 0; e < NEXP; e++) acc[e] = 0.f;
    #pragma unroll
    for (int j = 0; j < 4; j++) {
        const float* r8 = rw + (size_t)(tid * 4 + j) * NEXP;
        float4 ra = *(const float4*)r8;
        float4 rb = *(const float4*)(r8 + 4);
        float xv = vals[j];
        acc[0] += xv * ra.x; acc[1] += xv * ra.y; acc[2] += xv * ra.z; acc[3] += xv * ra.w;
        acc[4] += xv * rb.x; acc[5] += xv * rb.y; acc[6] += xv * rb.z; acc[7] += xv * rb.w;
    }
    #pragma unroll
    for (int e = 0; e < NEXP; e++)
        for (int off = 32; off > 0; off >>= 1) acc[e] += __shfl_down(acc[e], off);
    if ((tid & 63) == 0) {
        #pragma unroll
        for (int e = 0; e < NEXP; e++) lred[tid >> 6][e] = acc[e];
    }
    __syncthreads();
    if (tid == 0) {
        float l[NEXP];
        #pragma unroll
        for (int e = 0; e < NEXP; e++) l[e] = lred[0][e] + lred[1][e] + lred[2][e] + lred[3][e];
        float mx = l[0];
        #pragma unroll
        for (int e = 1; e < NEXP; e++) mx = fmaxf(mx, l[e]);
        float p[NEXP]; float s = 0.f;
        #pragma unroll
        for (int e = 0; e < NEXP; e++) { p[e] = __expf(l[e] - mx); s += p[e]; }
        int i0 = 0;
        #pragma unroll
        for (int e = 1; e < NEXP; e++) if (p[e] > p[i0]) i0 = e;
        int i1 = (i0 == 0) ? 1 : 0;
        #pragma unroll
        for (int e = 0; e < NEXP; e++) if (e != i0 && p[e] > p[i1]) i1 = e;
        float v0 = p[i0], v1 = p[i1], sn = v0 + v1;
        topEk[2 * t]     = i0; topW[2 * t]     = v0 / sn;
        topEk[2 * t + 1] = i1; topW[2 * t + 1] = v1 / sn;
        atomicAdd(&cnt[i0], 1);
        atomicAdd(&cnt[i1], 1);
    }
}

// ---------------------------------------------------------------- fused 4-way transpose fp32 [1024][1024] -> split bf16 [C][R]
// also zeroes the 16 routing counter ints (runs first in the launch sequence)
__global__ __launch_bounds__(256) void transpose_split4(
        const float* __restrict__ wq, const float* __restrict__ wk,
        const float* __restrict__ wv, const float* __restrict__ wo,
        __hip_bfloat16* __restrict__ qkvh, __hip_bfloat16* __restrict__ qkvl,
        __hip_bfloat16* __restrict__ oh, __hip_bfloat16* __restrict__ ol,
        int* __restrict__ zbuf) {
    int z = blockIdx.z;
    if (z == 0 && blockIdx.x == 0 && blockIdx.y == 0 && threadIdx.x < 16)
        zbuf[threadIdx.x] = 0;
    const float* src = (z == 0) ? wq : (z == 1) ? wk : (z == 2) ? wv : wo;
    __hip_bfloat16* dh = (z < 3) ? qkvh : oh;
    __hip_bfloat16* dl = (z < 3) ? qkvl : ol;
    int rowOff = (z < 3) ? z * HS : 0;
    const int R = HS, C = HS;
    __shared__ float tile[64][65];
    int c0 = blockIdx.x * 64, r0 = blockIdx.y * 64;
    int tx = threadIdx.x & 15, ty = threadIdx.x >> 4;
    #pragma unroll
    for (int p = 0; p < 4; p++) {
        int r = ty + p * 16;
        float4 v = *(const float4*)(src + (size_t)(r0 + r) * C + c0 + tx * 4);
        tile[r][tx * 4 + 0] = v.x; tile[r][tx * 4 + 1] = v.y;
        tile[r][tx * 4 + 2] = v.z; tile[r][tx * 4 + 3] = v.w;
    }
    __syncthreads();
    int cc0 = threadIdx.x >> 3, rr = (threadIdx.x & 7) * 8;
    #pragma unroll
    for (int p = 0; p < 2; p++) {
        int cc = cc0 + p * 32;
        u16x8 h8, l8;
        #pragma unroll
        for (int j = 0; j < 8; j++) {
            float v = tile[rr + j][cc];
            __hip_bfloat16 hi = __float2bfloat16(v);
            __hip_bfloat16 lo = __float2bfloat16(v - __bfloat162float(hi));
            h8[j] = *(unsigned short*)&hi;
            l8[j] = *(unsigned short*)&lo;
        }
        size_t o = (size_t)(rowOff + c0 + cc) * R + r0 + rr;
        *(u16x8*)&dh[o] = h8;
        *(u16x8*)&dl[o] = l8;
    }
}

// ---------------------------------------------------------------- all expert-weight transposes in one launch
// z = which*8 + e; which 0: w1 [HS][IS]->[IS][HS], 1: w3 same, 2: w2 [IS][HS]->[HS][IS]
__global__ __launch_bounds__(256) void transpose_b64_all(
        const float* __restrict__ w1, const float* __restrict__ w3, const float* __restrict__ w2,
        __hip_bfloat16* __restrict__ w1T, __hip_bfloat16* __restrict__ w3T,
        __hip_bfloat16* __restrict__ w2T) {
    int z = blockIdx.z, which = z >> 3, e = z & 7;
    int R = (which == 2) ? IS : HS;
    int C = (which == 2) ? HS : IS;
    int c0 = blockIdx.x * 64, r0 = blockIdx.y * 64;
    if (c0 >= C || r0 >= R) return;
    const float* srcb = (which == 0) ? w1 : (which == 1) ? w3 : w2;
    __hip_bfloat16* dstb = (which == 0) ? w1T : (which == 1) ? w3T : w2T;
    const float* src = srcb + (size_t)e * R * C;
    __hip_bfloat16* dst = dstb + (size_t)e * R * C;
    __shared__ float tile[64][65];
    int tx = threadIdx.x & 15, ty = threadIdx.x >> 4;
    #pragma unroll
    for (int p = 0; p < 4; p++) {
        int r = ty + p * 16;
        float4 v = *(const float4*)(src + (size_t)(r0 + r) * C + c0 + tx * 4);
        tile[r][tx * 4 + 0] = v.x; tile[r][tx * 4 + 1] = v.y;
        tile[r][tx * 4 + 2] = v.z; tile[r][tx * 4 + 3] = v.w;
    }
    __syncthreads();
    int cc0 = threadIdx.x >> 3, rr = (threadIdx.x & 7) * 8;
    #pragma unroll
    for (int p = 0; p < 2; p++) {
        int cc = cc0 + p * 32;
        u16x8 b8;
        #pragma unroll
        for (int j = 0; j < 8; j++) {
            __hip_bfloat16 hi = __float2bfloat16(tile[rr + j][cc]);
            b8[j] = *(unsigned short*)&hi;
        }
        *(u16x8*)&dst[(size_t)(c0 + cc) * R + r0 + rr] = b8;
    }
}

// ---------------------------------------------------------------- split-bf16 GEMM, 128x64 tile, dbuf DMA
// C[M][N] = (Ah+Al)[M][K] @ (Bh+Bl)[N][K]^T (+resid), via Ah@Bh + Ah@Bl + Al@Bh
__global__ __launch_bounds__(256) void gemm_bf16x3(const __hip_bfloat16* __restrict__ Ah,
                                                   const __hip_bfloat16* __restrict__ Al,
                                                   const __hip_bfloat16* __restrict__ Bh,
                                                   const __hip_bfloat16* __restrict__ Bl,
                                                   const float* __restrict__ resid,
                                                   float* __restrict__ C,
                                                   int M, int N, int K) {
    __shared__ __align__(16) short Ahs[2][128][32];   // 16 KB
    __shared__ __align__(16) short Als[2][128][32];   // 16 KB
    __shared__ __align__(16) short Bhs[2][64][32];    // 8 KB
    __shared__ __align__(16) short Bls[2][64][32];    // 8 KB -> 48 KB total
    int bm = blockIdx.y * 128, bn = blockIdx.x * 64;
    int t = threadIdx.x;
    int wave = t >> 6, lane = t & 63;
    int wm = (wave & 1) * 64, wn = (wave >> 1) * 32;
    int fr = lane & 15, quad = lane >> 4;
    int rA = wave * 32;            // A rows staged by this wave
    int rB = wave * 16;            // B rows staged by this wave
    int srow = lane >> 2;
    int schunk = (lane & 3) ^ ((lane >> 3) & 3);   // xor-swizzled 16B chunk
    const __hip_bfloat16* pAh0 = Ah + (size_t)(bm + rA + srow) * K + schunk * 8;
    const __hip_bfloat16* pAh1 = pAh0 + (size_t)16 * K;
    const __hip_bfloat16* pAl0 = Al + (size_t)(bm + rA + srow) * K + schunk * 8;
    const __hip_bfloat16* pAl1 = pAl0 + (size_t)16 * K;
    const __hip_bfloat16* pBh  = Bh + (size_t)(bn + rB + srow) * K + schunk * 8;
    const __hip_bfloat16* pBl  = Bl + (size_t)(bn + rB + srow) * K + schunk * 8;
    int ca = (quad ^ ((fr >> 1) & 3)) * 8;         // swizzled frag col (shorts)

    ldsdma16(&Ahs[0][rA][0],      pAh0);
    ldsdma16(&Ahs[0][rA + 16][0], pAh1);
    ldsdma16(&Als[0][rA][0],      pAl0);
    ldsdma16(&Als[0][rA + 16][0], pAl1);
    ldsdma16(&Bhs[0][rB][0],      pBh);
    ldsdma16(&Bls[0][rB][0],      pBl);

    f32x4 acc[4][2] = {};
    int NIT = K >> 5;
    for (int it = 0; it < NIT; it++) {
        int cur = it & 1;
        __syncthreads();
        if (it + 1 < NIT) {
            int k1 = (it + 1) << 5;
            int nxt = cur ^ 1;
            ldsdma16(&Ahs[nxt][rA][0],      pAh0 + k1);
            ldsdma16(&Ahs[nxt][rA + 16][0], pAh1 + k1);
            ldsdma16(&Als[nxt][rA][0],      pAl0 + k1);
            ldsdma16(&Als[nxt][rA + 16][0], pAl1 + k1);
            ldsdma16(&Bhs[nxt][rB][0],      pBh + k1);
            ldsdma16(&Bls[nxt][rB][0],      pBl + k1);
        }
        bf16x8 ah[4], bh[2], x[4];
        #pragma unroll
        for (int i = 0; i < 4; i++) ah[i] = *(const bf16x8*)&Ahs[cur][wm + i * 16 + fr][ca];
        #pragma unroll
        for (int i = 0; i < 2; i++) bh[i] = *(const bf16x8*)&Bhs[cur][wn + i * 16 + fr][ca];
        #pragma unroll
        for (int mi = 0; mi < 4; mi++)
            #pragma unroll
            for (int ni = 0; ni < 2; ni++)
                acc[mi][ni] = __builtin_amdgcn_mfma_f32_16x16x32_bf16(ah[mi], bh[ni], acc[mi][ni], 0, 0, 0);
        #pragma unroll
        for (int i = 0; i < 2; i++) x[i] = *(const bf16x8*)&Bls[cur][wn + i * 16 + fr][ca];
        #pragma unroll
        for (int mi = 0; mi < 4; mi++)
            #pragma unroll
            for (int ni = 0; ni < 2; ni++)
                acc[mi][ni] = __builtin_amdgcn_mfma_f32_16x16x32_bf16(ah[mi], x[ni], acc[mi][ni], 0, 0, 0);
        #pragma unroll
        for (int i = 0; i < 4; i++) x[i] = *(const bf16x8*)&Als[cur][wm + i * 16 + fr][ca];
        #pragma unroll
        for (int mi = 0; mi < 4; mi++)
            #pragma unroll
            for (int ni = 0; ni < 2; ni++)
                acc[mi][ni] = __builtin_amdgcn_mfma_f32_16x16x32_bf16(x[mi], bh[ni], acc[mi][ni], 0, 0, 0);
    }
    int rq = quad * 4;
    #pragma unroll
    for (int mi = 0; mi < 4; mi++) {
        #pragma unroll
        for (int r = 0; r < 4; r++) {
            size_t rowo = (size_t)(bm + wm + mi * 16 + rq + r) * N + bn + wn;
            #pragma unroll
            for (int ni = 0; ni < 2; ni++) {
                float v = acc[mi][ni][r];
                size_t o = rowo + ni * 16 + fr;
                if (resid) v += resid[o];
                C[o] = v;
            }
        }
    }
}

// ---------------------------------------------------------------- QKV GEMM with fused RoPE + split-bf16 epilogue
__global__ __launch_bounds__(256) void gemm_qkv_rope(const __hip_bfloat16* __restrict__ Ah,
                                                     const __hip_bfloat16* __restrict__ Al,
                                                     const __hip_bfloat16* __restrict__ Bh,
                                                     const __hip_bfloat16* __restrict__ Bl,
                                                     const float* __restrict__ fc,
                                                     __hip_bfloat16* __restrict__ qh, __hip_bfloat16* __restrict__ ql,
                                                     __hip_bfloat16* __restrict__ kh, __hip_bfloat16* __restrict__ kl,
                                                     __hip_bfloat16* __restrict__ vh, __hip_bfloat16* __restrict__ vl) {
    const int K = HS;
    __shared__ __align__(16) short Ahs[2][128][32];
    __shared__ __align__(16) short Als[2][128][32];
    __shared__ __align__(16) short Bhs[2][64][32];
    __shared__ __align__(16) short Bls[2][64][32];
    int bm = blockIdx.y * 128, bn = blockIdx.x * 64;
    int t = threadIdx.x;
    int wave = t >> 6, lane = t & 63;
    int wm = (wave & 1) * 64, wn = (wave >> 1) * 32;
    int fr = lane & 15, quad = lane >> 4;
    int rA = wave * 32;
    int rB = wave * 16;
    int srow = lane >> 2;
    int schunk = (lane & 3) ^ ((lane >> 3) & 3);
    const __hip_bfloat16* pAh0 = Ah + (size_t)(bm + rA + srow) * K + schunk * 8;
    const __hip_bfloat16* pAh1 = pAh0 + (size_t)16 * K;
    const __hip_bfloat16* pAl0 = Al + (size_t)(bm + rA + srow) * K + schunk * 8;
    const __hip_bfloat16* pAl1 = pAl0 + (size_t)16 * K;
    const __hip_bfloat16* pBh  = Bh + (size_t)(bn + rB + srow) * K + schunk * 8;
    const __hip_bfloat16* pBl  = Bl + (size_t)(bn + rB + srow) * K + schunk * 8;
    int ca = (quad ^ ((fr >> 1) & 3)) * 8;

    ldsdma16(&Ahs[0][rA][0],      pAh0);
    ldsdma16(&Ahs[0][rA + 16][0], pAh1);
    ldsdma16(&Als[0][rA][0],      pAl0);
    ldsdma16(&Als[0][rA + 16][0], pAl1);
    ldsdma16(&Bhs[0][rB][0],      pBh);
    ldsdma16(&Bls[0][rB][0],      pBl);

    f32x4 acc[4][2] = {};
    const int NIT = K >> 5;
    for (int it = 0; it < NIT; it++) {
        int cur = it & 1;
        __syncthreads();
        if (it + 1 < NIT) {
            int k1 = (it + 1) << 5;
            int nxt = cur ^ 1;
            ldsdma16(&Ahs[nxt][rA][0],      pAh0 + k1);
            ldsdma16(&Ahs[nxt][rA + 16][0], pAh1 + k1);
            ldsdma16(&Als[nxt][rA][0],      pAl0 + k1);
            ldsdma16(&Als[nxt][rA + 16][0], pAl1 + k1);
            ldsdma16(&Bhs[nxt][rB][0],      pBh + k1);
            ldsdma16(&Bls[nxt][rB][0],      pBl + k1);
        }
        bf16x8 ah[4], bh[2], x[4];
        #pragma unroll
        for (int i = 0; i < 4; i++) ah[i] = *(const bf16x8*)&Ahs[cur][wm + i * 16 + fr][ca];
        #pragma unroll
        for (int i = 0; i < 2; i++) bh[i] = *(const bf16x8*)&Bhs[cur][wn + i * 16 + fr][ca];
        #pragma unroll
        for (int mi = 0; mi < 4; mi++)
            #pragma unroll
            for (int ni = 0; ni < 2; ni++)
                acc[mi][ni] = __builtin_amdgcn_mfma_f32_16x16x32_bf16(ah[mi], bh[ni], acc[mi][ni], 0, 0, 0);
        #pragma unroll
        for (int i = 0; i < 2; i++) x[i] = *(const bf16x8*)&Bls[cur][wn + i * 16 + fr][ca];
        #pragma unroll
        for (int mi = 0; mi < 4; mi++)
            #pragma unroll
            for (int ni = 0; ni < 2; ni++)
                acc[mi][ni] = __builtin_amdgcn_mfma_f32_16x16x32_bf16(ah[mi], x[ni], acc[mi][ni], 0, 0, 0);
        #pragma unroll
        for (int i = 0; i < 4; i++) x[i] = *(const bf16x8*)&Als[cur][wm + i * 16 + fr][ca];
        #pragma unroll
        for (int mi = 0; mi < 4; mi++)
            #pragma unroll
            for (int ni = 0; ni < 2; ni++)
                acc[mi][ni] = __builtin_amdgcn_mfma_f32_16x16x32_bf16(x[mi], bh[ni], acc[mi][ni], 0, 0, 0);
    }
    // epilogue: block-uniform q/k/v selection (bn is a 64-aligned stripe)
    __hip_bfloat16 *dh, *dl;
    int cbase;
    bool dorope;
    if (bn < 1024)      { dh = qh; dl = ql; cbase = bn;        dorope = true;  }
    else if (bn < 2048) { dh = kh; dl = kl; cbase = bn - 1024; dorope = true;  }
    else                { dh = vh; dl = vl; cbase = bn - 2048; dorope = false; }
    float sgn = (fr & 1) ? 1.f : -1.f;
    int rq = quad * 4;
    #pragma unroll
    for (int mi = 0; mi < 4; mi++) {
        #pragma unroll
        for (int r = 0; r < 4; r++) {
            int trow = bm + wm + mi * 16 + rq + r;
            int s = trow & (SEQ - 1);
            size_t ob = (size_t)trow * HS + cbase;
            #pragma unroll
            for (int ni = 0; ni < 2; ni++) {
                float v = acc[mi][ni][r];
                int colh = wn + ni * 16 + fr;          // 0..63 within stripe = head pos
                float outv;
                if (dorope) {
                    float p = __shfl_xor(v, 1);
                    const float* fb = fc + (size_t)s * HDIM + (colh & ~1);
                    float cr = fb[0], ci = fb[1];
                    outv = v * cr + sgn * (p * ci);
                } else {
                    outv = v;
                }
                __hip_bfloat16 hi = __float2bfloat16(outv);
                __hip_bfloat16 lo = __float2bfloat16(outv - __bfloat162float(hi));
                dh[ob + colh] = hi;
                dl[ob + colh] = lo;
            }
        }
    }
}

// ---------------------------------------------------------------- split-K flash attention, MFMA split-bf16
__global__ __launch_bounds__(256) void attn_partial(
        const __hip_bfloat16* __restrict__ qh, const __hip_bfloat16* __restrict__ ql,
        const __hip_bfloat16* __restrict__ kh, const __hip_bfloat16* __restrict__ kl,
        const __hip_bfloat16* __restrict__ vh, const __hip_bfloat16* __restrict__ vl,
        float* __restrict__ po, float* __restrict__ pm_g, float* __restrict__ pl_g) {
    int c = blockIdx.x, qt = blockIdx.y;
    int nc = (qt + 4) >> 2;
    if (c >= nc) return;
    int bh = blockIdx.z;
    int b = bh >> 4, h = bh & 15;
    int t0 = c * 4, t1 = min(t0 + 4, qt + 1);
    int tid = threadIdx.x;
    int wave = tid >> 6, lane = tid & 63;
    int fr = lane & 15, quad = lane >> 4;
    int w16 = wave * 16;
    __shared__ __align__(16) short Qh[64][PAD], Ql[64][PAD];
    __shared__ __align__(16) short KPh[64][PAD], KPl[64][PAD];
    __shared__ __align__(16) short Vhs[64][PAD], Vls[64][PAD];
    size_t hoff = (size_t)h * HDIM;
    int sr = tid >> 2, sg = tid & 3;
    {
        const __hip_bfloat16* qp  = qh + (size_t)(b * SEQ + qt * 64 + sr) * HS + hoff;
        const __hip_bfloat16* qp2 = ql + (size_t)(b * SEQ + qt * 64 + sr) * HS + hoff;
        *(uint4*)&Qh[sr][sg * 8]       = *(const uint4*)(qp + sg * 8);
        *(uint4*)&Qh[sr][(sg + 4) * 8] = *(const uint4*)(qp + (sg + 4) * 8);
        *(uint4*)&Ql[sr][sg * 8]       = *(const uint4*)(qp2 + sg * 8);
        *(uint4*)&Ql[sr][(sg + 4) * 8] = *(const uint4*)(qp2 + (sg + 4) * 8);
    }
    f32x4 o[4] = {};
    float mrow[4], lrow[4];
    #pragma unroll
    for (int i = 0; i < 4; i++) { mrow[i] = -1e30f; lrow[i] = 0.f; }
    int key0 = (tid & 31) * 2, ds = tid >> 5;
    __syncthreads();

    for (int kt = t0; kt < t1; kt++) {
        int kbase = kt * 64;
        {
            const __hip_bfloat16* kp  = kh + (size_t)(b * SEQ + kbase + sr) * HS + hoff;
            const __hip_bfloat16* kp2 = kl + (size_t)(b * SEQ + kbase + sr) * HS + hoff;
            *(uint4*)&KPh[sr][sg * 8]       = *(const uint4*)(kp + sg * 8);
            *(uint4*)&KPh[sr][(sg + 4) * 8] = *(const uint4*)(kp + (sg + 4) * 8);
            *(uint4*)&KPl[sr][sg * 8]       = *(const uint4*)(kp2 + sg * 8);
            *(uint4*)&KPl[sr][(sg + 4) * 8] = *(const uint4*)(kp2 + (sg + 4) * 8);
        }
        {
            const __hip_bfloat16* v0 = vh + (size_t)(b * SEQ + kbase + key0) * HS + hoff + ds * 8;
            uint4 A = *(const uint4*)v0;
            uint4 Bv = *(const uint4*)(v0 + HS);
            const unsigned short* ap = (const unsigned short*)&A;
            const unsigned short* bp = (const unsigned short*)&Bv;
            #pragma unroll
            for (int j = 0; j < 8; j++)
                *(unsigned*)&Vhs[ds * 8 + j][key0] = (unsigned)ap[j] | ((unsigned)bp[j] << 16);
            const __hip_bfloat16* v2 = vl + (size_t)(b * SEQ + kbase + key0) * HS + hoff + ds * 8;
            uint4 A2 = *(const uint4*)v2;
            uint4 B2 = *(const uint4*)(v2 + HS);
            const unsigned short* ap2 = (const unsigned short*)&A2;
            const unsigned short* bp2 = (const unsigned short*)&B2;
            #pragma unroll
            for (int j = 0; j < 8; j++)
                *(unsigned*)&Vls[ds * 8 + j][key0] = (unsigned)ap2[j] | ((unsigned)bp2[j] << 16);
        }
        __syncthreads();

        f32x4 s[4] = {};
        #pragma unroll
        for (int ks = 0; ks < 2; ks++) {
            bf16x8 a_h = *(const bf16x8*)&Qh[w16 + fr][quad * 8 + ks * 32];
            bf16x8 a_l = *(const bf16x8*)&Ql[w16 + fr][quad * 8 + ks * 32];
            #pragma unroll
            for (int ni = 0; ni < 4; ni++) {
                bf16x8 b_h = *(const bf16x8*)&KPh[ni * 16 + fr][quad * 8 + ks * 32];
                bf16x8 b_l = *(const bf16x8*)&KPl[ni * 16 + fr][quad * 8 + ks * 32];
                s[ni] = __builtin_amdgcn_mfma_f32_16x16x32_bf16(a_h, b_h, s[ni], 0, 0, 0);
                s[ni] = __builtin_amdgcn_mfma_f32_16x16x32_bf16(a_h, b_l, s[ni], 0, 0, 0);
                s[ni] = __builtin_amdgcn_mfma_f32_16x16x32_bf16(a_l, b_h, s[ni], 0, 0, 0);
            }
        }
        int qg = qt * 64 + w16 + quad * 4;
        #pragma unroll
        for (int ni = 0; ni < 4; ni++) {
            int kg = kbase + ni * 16 + fr;
            #pragma unroll
            for (int r = 0; r < 4; r++)
                s[ni][r] = (kg > qg + r) ? -1e9f : s[ni][r] * 0.125f;
        }
        #pragma unroll
        for (int r = 0; r < 4; r++) {
            float mx = fmaxf(fmaxf(s[0][r], s[1][r]), fmaxf(s[2][r], s[3][r]));
            #pragma unroll
            for (int wd = 1; wd < 16; wd <<= 1) mx = fmaxf(mx, __shfl_xor(mx, wd));
            float nm = fmaxf(mrow[r], mx);
            float alpha = __expf(mrow[r] - nm);
            float rs = 0.f;
            #pragma unroll
            for (int ni = 0; ni < 4; ni++) { float e = __expf(s[ni][r] - nm); s[ni][r] = e; rs += e; }
            #pragma unroll
            for (int wd = 1; wd < 16; wd <<= 1) rs += __shfl_xor(rs, wd);
            lrow[r] = lrow[r] * alpha + rs;
            mrow[r] = nm;
            o[0][r] *= alpha; o[1][r] *= alpha; o[2][r] *= alpha; o[3][r] *= alpha;
        }
        __syncthreads();
        #pragma unroll
        for (int ni = 0; ni < 4; ni++)
            #pragma unroll
            for (int r = 0; r < 4; r++) {
                float pv = s[ni][r];
                __hip_bfloat16 hi = __float2bfloat16(pv);
                __hip_bfloat16 lo = __float2bfloat16(pv - __bfloat162float(hi));
                KPh[w16 + quad * 4 + r][ni * 16 + fr] = *(short*)&hi;
                KPl[w16 + quad * 4 + r][ni * 16 + fr] = *(short*)&lo;
            }
        #pragma unroll
        for (int ks = 0; ks < 2; ks++) {
            bf16x8 p_h = *(const bf16x8*)&KPh[w16 + fr][quad * 8 + ks * 32];
            bf16x8 p_l = *(const bf16x8*)&KPl[w16 + fr][quad * 8 + ks * 32];
            #pragma unroll
            for (int ni = 0; ni < 4; ni++) {
                bf16x8 v_h = *(const bf16x8*)&Vhs[ni * 16 + fr][quad * 8 + ks * 32];
                bf16x8 v_l = *(const bf16x8*)&Vls[ni * 16 + fr][quad * 8 + ks * 32];
                o[ni] = __builtin_amdgcn_mfma_f32_16x16x32_bf16(p_h, v_h, o[ni], 0, 0, 0);
                o[ni] = __builtin_amdgcn_mfma_f32_16x16x32_bf16(p_h, v_l, o[ni], 0, 0, 0);
                o[ni] = __builtin_amdgcn_mfma_f32_16x16x32_bf16(p_l, v_h, o[ni], 0, 0, 0);
            }
        }
        __syncthreads();
    }
    int pidx = (bh * 16 + qt) * 4 + c;
    float* pob = po + (size_t)pidx * 4096;
    #pragma unroll
    for (int ni = 0; ni < 4; ni++)
        #pragma unroll
        for (int r = 0; r < 4; r++)
            pob[(w16 + quad * 4 + r) * 64 + ni * 16 + fr] = o[ni][r];
    if (fr == 0) {
        #pragma unroll
        for (int r = 0; r < 4; r++) {
            pm_g[pidx * 64 + w16 + quad * 4 + r] = mrow[r];
            pl_g[pidx * 64 + w16 + quad * 4 + r] = lrow[r];
        }
    }
}

// ---------------------------------------------------------------- merge partials -> ctx as split bf16
__global__ void attn_merge(const float* __restrict__ po, const float* __restrict__ pm,
                           const float* __restrict__ pl,
                           __hip_bfloat16* __restrict__ ch, __hip_bfloat16* __restrict__ cl) {
    int qt = blockIdx.x, h = blockIdx.y, b = blockIdx.z;
    int bh = b * 16 + h;
    int nc = (qt + 4) >> 2;
    int base = (bh * 16 + qt) * 4;
    int tid = threadIdx.x;
    int r  = tid >> 2;
    int d0 = (tid & 3) * 16;
    float mstar = -1e30f;
    for (int c = 0; c < nc; c++) mstar = fmaxf(mstar, pm[(base + c) * 64 + r]);
    float a[4];
    float lsum = 0.f;
    for (int c = 0; c < nc; c++) {
        a[c] = __expf(pm[(base + c) * 64 + r] - mstar);
        lsum += a[c] * pl[(base + c) * 64 + r];
    }
    float inv = 1.f / lsum;
    size_t crow = (size_t)(b * SEQ + qt * 64 + r) * HS + h * HDIM;
    for (int dd = 0; dd < 16; dd += 4) {
        float4 acc = make_float4(0.f, 0.f, 0.f, 0.f);
        for (int c = 0; c < nc; c++) {
            float4 v = *(const float4*)(po + (size_t)(base + c) * 4096 + r * 64 + d0 + dd);
            acc.x += a[c] * v.x; acc.y += a[c] * v.y;
            acc.z += a[c] * v.z; acc.w += a[c] * v.w;
        }
        float vs[4] = {acc.x * inv, acc.y * inv, acc.z * inv, acc.w * inv};
        #pragma unroll
        for (int j = 0; j < 4; j++) {
            __hip_bfloat16 hi = __float2bfloat16(vs[j]);
            ch[crow + d0 + dd + j] = hi;
            cl[crow + d0 + dd + j] = __float2bfloat16(vs[j] - __bfloat162float(hi));
        }
    }
}

// ---------------------------------------------------------------- offsets + block table
__global__ void offsets_kernel(const int* __restrict__ cnt, int* __restrict__ off,
                               int* __restrict__ blk_e, int* __restrict__ blk_r) {
    if (threadIdx.x == 0) {
        int o = 0, n = 0;
        for (int e = 0; e < NEXP; e++) {
            off[e] = o;
            for (int bm = 0; bm < cnt[e]; bm += 128) { blk_e[n] = e; blk_r[n] = bm; n++; }
            o += cnt[e];
        }
        for (; n < MAXBLK; n++) { blk_e[n] = -1; blk_r[n] = 0; }
    }
}

__global__ void scatter_kernel(const int* __restrict__ topEk, int* __restrict__ fill,
                               const int* __restrict__ off, const float* __restrict__ topW,
                               int* __restrict__ tok_list, int* __restrict__ inv) {
    int idx = blockIdx.x * 256 + threadIdx.x;
    int e = topEk[idx];
    int slot = atomicAdd(&fill[e], 1);
    int gidx = off[e] + slot;
    tok_list[gidx] = idx >> 1;
    inv[idx] = gidx;
}

// ---------------------------------------------------------------- MoE up-proj, 128x64 tile, dbuf DMA
__global__ __launch_bounds__(256) void moe_up_mfma(const __hip_bfloat16* __restrict__ Abf,
                                                   const __hip_bfloat16* __restrict__ B1T,
                                                   const __hip_bfloat16* __restrict__ B3T,
                                                   __hip_bfloat16* __restrict__ g,
                                                   const int* __restrict__ cnt,
                                                   const int* __restrict__ off,
                                                   const int* __restrict__ tok_list,
                                                   const int* __restrict__ blk_e,
                                                   const int* __restrict__ blk_r) {
    int e = blk_e[blockIdx.y];
    if (e < 0) return;
    int bm = blk_r[blockIdx.y];
    int ce = cnt[e], oe = off[e];
    int bn = blockIdx.x * 64;
    const __hip_bfloat16* b1 = B1T + (size_t)e * IS * HS;   // [IS][HS]
    const __hip_bfloat16* b3 = B3T + (size_t)e * IS * HS;

    __shared__ __align__(16) short As[2][128][32];    // 16 KB
    __shared__ __align__(16) short B1s[2][64][32];    // 8 KB
    __shared__ __align__(16) short B3s[2][64][32];    // 8 KB -> 32 KB

    int t = threadIdx.x;
    int wave = t >> 6, lane = t & 63;
    int wm = (wave & 1) * 64, wn = (wave >> 1) * 32;
    int fr = lane & 15, quad = lane >> 4;
    int rA = wave * 32, rB = wave * 16;
    int srow = lane >> 2;
    int schunk = (lane & 3) ^ ((lane >> 3) & 3);
    int tokA0 = tok_list[oe + min(bm + rA + srow, ce - 1)];
    int tokA1 = tok_list[oe + min(bm + rA + 16 + srow, ce - 1)];
    const __hip_bfloat16* pA0 = Abf + (size_t)tokA0 * HS + schunk * 8;
    const __hip_bfloat16* pA1 = Abf + (size_t)tokA1 * HS + schunk * 8;
    const __hip_bfloat16* pB1 = b1 + (size_t)(bn + rB + srow) * HS + schunk * 8;
    const __hip_bfloat16* pB3 = b3 + (size_t)(bn + rB + srow) * HS + schunk * 8;
    int ca = (quad ^ ((fr >> 1) & 3)) * 8;

    ldsdma16(&As[0][rA][0],      pA0);
    ldsdma16(&As[0][rA + 16][0], pA1);
    ldsdma16(&B1s[0][rB][0],     pB1);
    ldsdma16(&B3s[0][rB][0],     pB3);

    f32x4 acc1[4][2] = {};
    f32x4 acc3[4][2] = {};
    const int NIT = HS >> 5;
    for (int it = 0; it < NIT; it++) {
        int cur = it & 1;
        __syncthreads();
        if (it + 1 < NIT) {
            int k1 = (it + 1) << 5;
            int nxt = cur ^ 1;
            ldsdma16(&As[nxt][rA][0],      pA0 + k1);
            ldsdma16(&As[nxt][rA + 16][0], pA1 + k1);
            ldsdma16(&B1s[nxt][rB][0],     pB1 + k1);
            ldsdma16(&B3s[nxt][rB][0],     pB3 + k1);
        }
        bf16x8 a[4], f1[2], f3[2];
        #pragma unroll
        for (int i = 0; i < 4; i++) a[i] = *(const bf16x8*)&As[cur][wm + i * 16 + fr][ca];
        #pragma unroll
        for (int i = 0; i < 2; i++) {
            f1[i] = *(const bf16x8*)&B1s[cur][wn + i * 16 + fr][ca];
            f3[i] = *(const bf16x8*)&B3s[cur][wn + i * 16 + fr][ca];
        }
        #pragma unroll
        for (int mi = 0; mi < 4; mi++)
            #pragma unroll
            for (int ni = 0; ni < 2; ni++) {
                acc1[mi][ni] = __builtin_amdgcn_mfma_f32_16x16x32_bf16(a[mi], f1[ni], acc1[mi][ni], 0, 0, 0);
                acc3[mi][ni] = __builtin_amdgcn_mfma_f32_16x16x32_bf16(a[mi], f3[ni], acc3[mi][ni], 0, 0, 0);
            }
    }
    int rq = quad * 4;
    #pragma unroll
    for (int mi = 0; mi < 4; mi++) {
        #pragma unroll
        for (int r = 0; r < 4; r++) {
            int slot = bm + wm + mi * 16 + rq + r;
            if (slot < ce) {
                size_t rowo = (size_t)(oe + slot) * IS + bn + wn;
                #pragma unroll
                for (int ni = 0; ni < 2; ni++) {
                    float x1 = acc1[mi][ni][r];
                    float x3 = acc3[mi][ni][r];
                    float sv = (x1 / (1.f + __expf(-x1))) * x3;
                    g[rowo + ni * 16 + fr] = __float2bfloat16(sv);
                }
            }
        }
    }
}

// ---------------------------------------------------------------- MoE down-proj, 128x64 tile, split-K=2, scratch (no atomics)
__global__ __launch_bounds__(256) void moe_down_mfma(const __hip_bfloat16* __restrict__ g,
                                                     const __hip_bfloat16* __restrict__ B2T,
                                                     float* __restrict__ scr,
                                                     const int* __restrict__ cnt,
                                                     const int* __restrict__ off,
                                                     const int* __restrict__ blk_e,
                                                     const int* __restrict__ blk_r) {
    int e = blk_e[blockIdx.y];
    if (e < 0) return;
    int bm = blk_r[blockIdx.y];
    int ce = cnt[e], oe = off[e];
    int bn = blockIdx.x * 64;
    int kz = blockIdx.z * (IS / 2);           // split-K half
    const __hip_bfloat16* b2 = B2T + (size_t)e * HS * IS;   // [HS][IS]

    __shared__ __align__(16) short As[2][128][32];   // 16 KB
    __shared__ __align__(16) short Bs[2][64][32];    // 8 KB -> 24 KB

    int t = threadIdx.x;
    int wave = t >> 6, lane = t & 63;
    int wm = (wave & 1) * 64, wn = (wave >> 1) * 32;
    int fr = lane & 15, quad = lane >> 4;
    int rA = wave * 32, rB = wave * 16;
    int srow = lane >> 2;
    int schunk = (lane & 3) ^ ((lane >> 3) & 3);
    int ga0 = oe + min(bm + rA + srow, ce - 1);
    int ga1 = oe + min(bm + rA + 16 + srow, ce - 1);
    const __hip_bfloat16* pA0 = g + (size_t)ga0 * IS + kz + schunk * 8;
    const __hip_bfloat16* pA1 = g + (size_t)ga1 * IS + kz + schunk * 8;
    const __hip_bfloat16* pB  = b2 + (size_t)(bn + rB + srow) * IS + kz + schunk * 8;
    int ca = (quad ^ ((fr >> 1) & 3)) * 8;

    ldsdma16(&As[0][rA][0],      pA0);
    ldsdma16(&As[0][rA + 16][0], pA1);
    ldsdma16(&Bs[0][rB][0],      pB);

    f32x4 acc[4][2] = {};
    const int NIT = (IS / 2) >> 5;
    for (int it = 0; it < NIT; it++) {
        int cur = it & 1;
        __syncthreads();
        if (it + 1 < NIT) {
            int k1 = (it + 1) << 5;
            int nxt = cur ^ 1;
            ldsdma16(&As[nxt][rA][0],      pA0 + k1);
            ldsdma16(&As[nxt][rA + 16][0], pA1 + k1);
            ldsdma16(&Bs[nxt][rB][0],      pB + k1);
        }
        bf16x8 a[4], f[2];
        #pragma unroll
        for (int i = 0; i < 4; i++) a[i] = *(const bf16x8*)&As[cur][wm + i * 16 + fr][ca];
        #pragma unroll
        for (int i = 0; i < 2; i++) f[i] = *(const bf16x8*)&Bs[cur][wn + i * 16 + fr][ca];
        #pragma unroll
        for (int mi = 0; mi < 4; mi++)
            #pragma unroll
            for (int ni = 0; ni < 2; ni++)
                acc[mi][ni] = __builtin_amdgcn_mfma_f32_16x16x32_bf16(a[mi], f[ni], acc[mi][ni], 0, 0, 0);
    }
    int rq = quad * 4;
    #pragma unroll
    for (int mi = 0; mi < 4; mi++) {
        #pragma unroll
        for (int r = 0; r < 4; r++) {
            int slot = bm + wm + mi * 16 + rq + r;
            if (slot < ce) {
                int gidx = oe + slot;
                size_t rowo = (size_t)(blockIdx.z * NASSIGN + gidx) * HS + bn + wn;
                #pragma unroll
                for (int ni = 0; ni < 2; ni++)
                    scr[rowo + ni * 16 + fr] = acc[mi][ni][r];
            }
        }
    }
}

// ---------------------------------------------------------------- gather: out[t] = h[t] + sum_k w_k * (p0[g_k] + p1[g_k])
__global__ void moe_gather(const float* __restrict__ scr, const int* __restrict__ inv,
                           const float* __restrict__ topW, float* __restrict__ out) {
    int t = blockIdx.x;
    int c = threadIdx.x * 4;
    int g0 = inv[2 * t], g1 = inv[2 * t + 1];
    float w0 = topW[2 * t], w1 = topW[2 * t + 1];
    size_t o = (size_t)t * HS + c;
    float4 h4 = *(const float4*)(out + o);
    float4 a0 = *(const float4*)(scr + (size_t)g0 * HS + c);
    float4 a1 = *(const float4*)(scr + (size_t)(NASSIGN + g0) * HS + c);
    float4 b0 = *(const float4*)(scr + (size_t)g1 * HS + c);
    float4 b1 = *(const float4*)(scr + (size_t)(NASSIGN + g1) * HS + c);
    float4 r;
    r.x = h4.x + w0 * (a0.x + a1.x) + w1 * (b0.x + b1.x);
    r.y = h4.y + w0 * (a0.y + a1.y) + w1 * (b0.y + b1.y);
    r.z = h4.z + w0 * (a0.z + a1.z) + w1 * (b0.z + b1.z);
    r.w = h4.w + w0 * (a0.w + a1.w) + w1 * (b0.w + b1.w);
    *(float4*)(out + o) = r;
}

// ---------------------------------------------------------------- launch
extern "C" void kernel_launch(void* const* d_in, const int* in_sizes, int n_in,
                              void* d_out, int out_size, void* d_ws, size_t ws_size,
                              hipStream_t stream) {
    const float* x   = (const float*)d_in[0];
    const float* anw = (const float*)d_in[1];
    const float* fnw = (const float*)d_in[2];
    const float* wq  = (const float*)d_in[3];
    const float* wk  = (const float*)d_in[4];
    const float* wv  = (const float*)d_in[5];
    const float* wo  = (const float*)d_in[6];
    const float* rw  = (const float*)d_in[7];
    const float* w1  = (const float*)d_in[8];
    const float* w3  = (const float*)d_in[9];
    const float* w2  = (const float*)d_in[10];
    const float* fc  = (const float*)d_in[11];
    float* out = (float*)d_out;

    char* ws = (char*)d_ws;
    const size_t MB = 1024 * 1024;
    __hip_bfloat16* xn_h  = (__hip_bfloat16*)(ws + 0 * MB);
    __hip_bfloat16* xn_l  = (__hip_bfloat16*)(ws + 4 * MB);
    __hip_bfloat16* WqT_h = (__hip_bfloat16*)(ws + 32 * MB);
    __hip_bfloat16* WqT_l = (__hip_bfloat16*)(ws + 38 * MB);
    __hip_bfloat16* woT_h = (__hip_bfloat16*)(ws + 44 * MB);
    __hip_bfloat16* woT_l = (__hip_bfloat16*)(ws + 46 * MB);
    float*          po    = (float*)(ws + 48 * MB);      // attn partials [48,80)
    float*          pm    = (float*)(ws + 82 * MB);
    float*          plb   = (float*)(ws + 83 * MB);
    __hip_bfloat16* ctx_h = (__hip_bfloat16*)(ws + 84 * MB);
    __hip_bfloat16* ctx_l = (__hip_bfloat16*)(ws + 88 * MB);
    __hip_bfloat16* qhb   = (__hip_bfloat16*)(ws + 92 * MB);
    __hip_bfloat16* qlb   = (__hip_bfloat16*)(ws + 96 * MB);
    __hip_bfloat16* khb   = (__hip_bfloat16*)(ws + 100 * MB);
    __hip_bfloat16* klb   = (__hip_bfloat16*)(ws + 104 * MB);
    __hip_bfloat16* vhb   = (__hip_bfloat16*)(ws + 108 * MB);
    __hip_bfloat16* vlb   = (__hip_bfloat16*)(ws + 112 * MB);
    __hip_bfloat16* hn_bf = (__hip_bfloat16*)(ws + 8 * MB);    // [8,12)
    __hip_bfloat16* w1T   = (__hip_bfloat16*)(ws + 12 * MB);   // [12,44)  dead after moe_up
    float*          dscr  = (float*)(ws + 12 * MB);            // [12,44)  moe_down scratch (reuses w1T)
    __hip_bfloat16* w3T   = (__hip_bfloat16*)(ws + 44 * MB);   // [44,76)
    __hip_bfloat16* w2T   = (__hip_bfloat16*)(ws + 76 * MB);   // [76,108)
    __hip_bfloat16* gact  = (__hip_bfloat16*)(ws + 108 * MB);  // [108,124)
    int* ibase    = (int*)(ws + 124 * MB);
    int* cnt      = ibase;                 // 8
    int* fill     = ibase + 8;             // 8
    int* off      = ibase + 16;            // 8
    int* blk_e    = ibase + 24;            // 40
    int* blk_r    = ibase + 64;            // 40
    int* topEk    = ibase + 128;           // 4096
    int* tok_list = ibase + 128 + NASSIGN; // 4096
    float* topW   = (float*)(ibase + 128 + 2 * NASSIGN);
    int*   inv    = ibase + 128 + 3 * NASSIGN;   // 4096: assignment index per (token, k)

    // ---- attention half ----
    transpose_split4<<<dim3(HS / 64, HS / 64, 4), 256, 0, stream>>>(
        wq, wk, wv, wo, WqT_h, WqT_l, woT_h, woT_l, cnt);
    rmsnorm_split<<<NTOK, 256, 0, stream>>>(x, anw, xn_h, xn_l);

    gemm_qkv_rope<<<dim3(QKVW / 64, NTOK / 128), 256, 0, stream>>>(
        xn_h, xn_l, WqT_h, WqT_l, fc, qhb, qlb, khb, klb, vhb, vlb);

    attn_partial<<<dim3(4, 16, 32), 256, 0, stream>>>(qhb, qlb, khb, klb, vhb, vlb, po, pm, plb);
    attn_merge<<<dim3(16, 16, 2), 256, 0, stream>>>(po, pm, plb, ctx_h, ctx_l);

    gemm_bf16x3<<<dim3(HS / 64, NTOK / 128), 256, 0, stream>>>(
        ctx_h, ctx_l, woT_h, woT_l, x, out, NTOK, HS, HS);   // out = h = x + ctx@wo

    // ---- MoE half (routed top-2, bf16 MFMA experts) ----
    rmsnorm_router<<<NTOK, 256, 0, stream>>>(out, fnw, rw, hn_bf, cnt, topEk, topW);
    transpose_b64_all<<<dim3(IS / 64, IS / 64, 24), 256, 0, stream>>>(
        w1, w3, w2, w1T, w3T, w2T);

    offsets_kernel<<<1, 64, 0, stream>>>(cnt, off, blk_e, blk_r);
    scatter_kernel<<<NASSIGN / 256, 256, 0, stream>>>(topEk, fill, off, topW, tok_list, inv);

    moe_up_mfma<<<dim3(IS / 64, MAXBLK), 256, 0, stream>>>(
        hn_bf, w1T, w3T, gact, cnt, off, tok_list, blk_e, blk_r);
    moe_down_mfma<<<dim3(HS / 64, MAXBLK, 2), 256, 0, stream>>>(
        gact, w2T, dscr, cnt, off, blk_e, blk_r);
    moe_gather<<<NTOK, 256, 0, stream>>>(dscr, inv, topW, out);
}

// Round 8
// 602.088 us; speedup vs baseline: 1.0673x; 1.0123x over previous
//
#include <hip/hip_runtime.h>
#include <hip/hip_bf16.h>
#include <math.h>

#define HS 1024      // hidden size
#define IS 2048      // intermediate size
#define NHEAD 16
#define HDIM 64
#define NEXP 8
#define BATCH 2
#define SEQ 1024
#define NTOK (BATCH*SEQ)     // 2048 tokens
#define NASSIGN (NTOK*2)     // 4096 (token, expert) assignments
#define QKVW 3072            // fused qkv row width
#define PAD 72               // LDS row stride for attn (bf16 elems)
#define MAXBLK 40            // max 128-row blocks over all experts

typedef short bf16x8 __attribute__((ext_vector_type(8)));
typedef float f32x4  __attribute__((ext_vector_type(4)));
typedef unsigned short u16x8 __attribute__((ext_vector_type(8)));
typedef unsigned short u16x4 __attribute__((ext_vector_type(4)));

// async global->LDS, 16B per lane; lds dest = base + lane*16 (wave-uniform base)
__device__ __forceinline__ void ldsdma16(void* lds, const void* gp) {
    __builtin_amdgcn_global_load_lds(
        (const __attribute__((address_space(1))) void*)gp,
        (__attribute__((address_space(3))) void*)lds, 16, 0, 0);
}

// ---------------------------------------------------------------- rmsnorm -> split bf16 (hi+lo)
__global__ void rmsnorm_split(const float* __restrict__ x, const float* __restrict__ w,
                              __hip_bfloat16* __restrict__ oh, __hip_bfloat16* __restrict__ ol) {
    int t = blockIdx.x;
    int tid = threadIdx.x;
    const float* row = x + (size_t)t * HS;
    float4 v4 = *(const float4*)(row + tid * 4);
    float ss = v4.x * v4.x + v4.y * v4.y + v4.z * v4.z + v4.w * v4.w;
    for (int off = 32; off > 0; off >>= 1) ss += __shfl_down(ss, off);
    __shared__ float red[4];
    if ((tid & 63) == 0) red[tid >> 6] = ss;
    __syncthreads();
    float tot = red[0] + red[1] + red[2] + red[3];
    float rr = rsqrtf(tot / (float)HS + 1e-6f);
    float4 w4 = *(const float4*)(w + tid * 4);
    float vals[4] = {w4.x * v4.x * rr, w4.y * v4.y * rr, w4.z * v4.z * rr, w4.w * v4.w * rr};
    u16x4 h4, l4;
    #pragma unroll
    for (int j = 0; j < 4; j++) {
        __hip_bfloat16 hi = __float2bfloat16(vals[j]);
        __hip_bfloat16 lo = __float2bfloat16(vals[j] - __bfloat162float(hi));
        h4[j] = *(unsigned short*)&hi;
        l4[j] = *(unsigned short*)&lo;
    }
    *(u16x4*)&oh[(size_t)t * HS + tid * 4] = h4;
    *(u16x4*)&ol[(size_t)t * HS + tid * 4] = l4;
}

// ---------------------------------------------------------------- fused rmsnorm (bf16 out) + router top-2
__global__ void rmsnorm_router(const float* __restrict__ x, const float* __restrict__ w,
                               const float* __restrict__ rw,
                               __hip_bfloat16* __restrict__ outb,
                               int* __restrict__ cnt, int* __restrict__ topEk,
                               float* __restrict__ topW) {
    int t = blockIdx.x;
    int tid = threadIdx.x;
    const float* row = x + (size_t)t * HS;
    float4 v4 = *(const float4*)(row + tid * 4);
    float ss = v4.x * v4.x + v4.y * v4.y + v4.z * v4.z + v4.w * v4.w;
    for (int off = 32; off > 0; off >>= 1) ss += __shfl_down(ss, off);
    __shared__ float red[4];
    __shared__ float lred[4][NEXP];
    if ((tid & 63) == 0) red[tid >> 6] = ss;
    __syncthreads();
    float tot = red[0] + red[1] + red[2] + red[3];
    float rr = rsqrtf(tot / (float)HS + 1e-6f);
    float4 w4 = *(const float4*)(w + tid * 4);
    float vals[4] = {w4.x * v4.x * rr, w4.y * v4.y * rr, w4.z * v4.z * rr, w4.w * v4.w * rr};
    u16x4 b4;
    #pragma unroll
    for (int j = 0; j < 4; j++) {
        __hip_bfloat16 hi = __float2bfloat16(vals[j]);
        b4[j] = *(unsigned short*)&hi;
    }
    *(u16x4*)&outb[(size_t)t * HS + tid * 4] = b4;
    // router logits: acc_e += x_norm[i] * rw[i][e]
    float acc[NEXP];
    #pragma unroll
    for (int e = 0; e < NEXP; e++) acc[e] = 0.f;
    #pragma unroll
    for (int j = 0; j < 4; j++) {
        const float* r8 = rw + (size_t)(tid * 4 + j) * NEXP;
        float4 ra = *(const float4*)r8;
        float4 rb = *(const float4*)(r8 + 4);
        float xv = vals[j];
        acc[0] += xv * ra.x; acc[1] += xv * ra.y; acc[2] += xv * ra.z; acc[3] += xv * ra.w;
        acc[4] += xv * rb.x; acc[5] += xv * rb.y; acc[6] += xv * rb.z; acc[7] += xv * rb.w;
    }
    #pragma unroll
    for (int e = 0; e < NEXP; e++)
        for (int off = 32; off > 0; off >>= 1) acc[e] += __shfl_down(acc[e], off);
    if ((tid & 63) == 0) {
        #pragma unroll
        for (int e = 0; e < NEXP; e++) lred[tid >> 6][e] = acc[e];
    }
    __syncthreads();
    if (tid == 0) {
        float l[NEXP];
        #pragma unroll
        for (int e = 0; e < NEXP; e++) l[e] = lred[0][e] + lred[1][e] + lred[2][e] + lred[3][e];
        float mx = l[0];
        #pragma unroll
        for (int e = 1; e < NEXP; e++) mx = fmaxf(mx, l[e]);
        float p[NEXP]; float s = 0.f;
        #pragma unroll
        for (int e = 0; e < NEXP; e++) { p[e] = __expf(l[e] - mx); s += p[e]; }
        int i0 = 0;
        #pragma unroll
        for (int e = 1; e < NEXP; e++) if (p[e] > p[i0]) i0 = e;
        int i1 = (i0 == 0) ? 1 : 0;
        #pragma unroll
        for (int e = 0; e < NEXP; e++) if (e != i0 && p[e] > p[i1]) i1 = e;
        float v0 = p[i0], v1 = p[i1], sn = v0 + v1;
        topEk[2 * t]     = i0; topW[2 * t]     = v0 / sn;
        topEk[2 * t + 1] = i1; topW[2 * t + 1] = v1 / sn;
        atomicAdd(&cnt[i0], 1);
        atomicAdd(&cnt[i1], 1);
    }
}

// ---------------------------------------------------------------- 128x64 transpose core (fp32 [K][N] -> bf16 [N][K])
// LDS tile[128][65] with XOR column-block swizzle: value (k,n) at col 4*((n>>2)^((k>>3)&15)) + (n&3).
// Load: 256-B read rows; Write: 256-B segments (16 lanes x u16x8 per output row).

// fused 4-way transpose of wq/wk/wv/wo -> split bf16 [C][R]; also zeroes 16 counter ints
__global__ __launch_bounds__(256) void transpose_split4(
        const float* __restrict__ wq, const float* __restrict__ wk,
        const float* __restrict__ wv, const float* __restrict__ wo,
        __hip_bfloat16* __restrict__ qkvh, __hip_bfloat16* __restrict__ qkvl,
        __hip_bfloat16* __restrict__ oh, __hip_bfloat16* __restrict__ ol,
        int* __restrict__ zbuf) {
    int z = blockIdx.z;
    if (z == 0 && blockIdx.x == 0 && threadIdx.x < 16)
        zbuf[threadIdx.x] = 0;
    const float* src = (z == 0) ? wq : (z == 1) ? wk : (z == 2) ? wv : wo;
    __hip_bfloat16* dh = (z < 3) ? qkvh : oh;
    __hip_bfloat16* dl = (z < 3) ? qkvl : ol;
    int rowOff = (z < 3) ? z * HS : 0;
    // tiles: 8 (K/128) x 16 (N/64) = 128 per z
    int id = blockIdx.x;
    int kt = id >> 4, nt = id & 15;
    int k0 = kt * 128, n0 = nt * 64;
    __shared__ float tile[128][65];
    int tx = threadIdx.x & 15, ty = threadIdx.x >> 4;   // ty 0..15
    #pragma unroll
    for (int p = 0; p < 8; p++) {
        int k = ty + p * 16;
        float4 v = *(const float4*)(src + (size_t)(k0 + k) * HS + n0 + tx * 4);
        int cb = 4 * (tx ^ ((k >> 3) & 15));
        tile[k][cb + 0] = v.x; tile[k][cb + 1] = v.y;
        tile[k][cb + 2] = v.z; tile[k][cb + 3] = v.w;
    }
    __syncthreads();
    int g = threadIdx.x & 15;
    #pragma unroll
    for (int it = 0; it < 4; it++) {
        int n = (threadIdx.x >> 4) + it * 16;
        int col = 4 * ((n >> 2) ^ g) + (n & 3);
        u16x8 h8, l8;
        #pragma unroll
        for (int j = 0; j < 8; j++) {
            float v = tile[8 * g + j][col];
            __hip_bfloat16 hi = __float2bfloat16(v);
            __hip_bfloat16 lo = __float2bfloat16(v - __bfloat162float(hi));
            h8[j] = *(unsigned short*)&hi;
            l8[j] = *(unsigned short*)&lo;
        }
        size_t o = (size_t)(rowOff + n0 + n) * HS + k0 + 8 * g;
        *(u16x8*)&dh[o] = h8;
        *(u16x8*)&dl[o] = l8;
    }
}

// all expert-weight transposes in one launch: z = which (0:w1, 1:w3, 2:w2), y = expert
__global__ __launch_bounds__(256) void transpose_b64_all(
        const float* __restrict__ w1, const float* __restrict__ w3, const float* __restrict__ w2,
        __hip_bfloat16* __restrict__ w1T, __hip_bfloat16* __restrict__ w3T,
        __hip_bfloat16* __restrict__ w2T) {
    int which = blockIdx.z, e = blockIdx.y;
    int Kd = (which == 2) ? IS : HS;   // src rows
    int Nd = (which == 2) ? HS : IS;   // src cols (contiguous)
    const float* srcb = (which == 0) ? w1 : (which == 1) ? w3 : w2;
    __hip_bfloat16* dstb = (which == 0) ? w1T : (which == 1) ? w3T : w2T;
    const float* src = srcb + (size_t)e * Kd * Nd;
    __hip_bfloat16* dst = dstb + (size_t)e * Kd * Nd;
    // 256 tiles of 128(K) x 64(N) per (which, expert)
    int id = blockIdx.x;
    int ntn = Nd >> 6;                 // 32 or 16
    int kt = id / ntn, nt = id % ntn;
    int k0 = kt * 128, n0 = nt * 64;
    __shared__ float tile[128][65];
    int tx = threadIdx.x & 15, ty = threadIdx.x >> 4;
    #pragma unroll
    for (int p = 0; p < 8; p++) {
        int k = ty + p * 16;
        float4 v = *(const float4*)(src + (size_t)(k0 + k) * Nd + n0 + tx * 4);
        int cb = 4 * (tx ^ ((k >> 3) & 15));
        tile[k][cb + 0] = v.x; tile[k][cb + 1] = v.y;
        tile[k][cb + 2] = v.z; tile[k][cb + 3] = v.w;
    }
    __syncthreads();
    int g = threadIdx.x & 15;
    #pragma unroll
    for (int it = 0; it < 4; it++) {
        int n = (threadIdx.x >> 4) + it * 16;
        int col = 4 * ((n >> 2) ^ g) + (n & 3);
        u16x8 b8;
        #pragma unroll
        for (int j = 0; j < 8; j++) {
            __hip_bfloat16 hi = __float2bfloat16(tile[8 * g + j][col]);
            b8[j] = *(unsigned short*)&hi;
        }
        *(u16x8*)&dst[(size_t)(n0 + n) * Kd + k0 + 8 * g] = b8;
    }
}

// ---------------------------------------------------------------- split-bf16 GEMM, 128x64 tile, dbuf DMA
// C[M][N] = (Ah+Al)[M][K] @ (Bh+Bl)[N][K]^T (+resid), via Ah@Bh + Ah@Bl + Al@Bh
__global__ __launch_bounds__(256) void gemm_bf16x3(const __hip_bfloat16* __restrict__ Ah,
                                                   const __hip_bfloat16* __restrict__ Al,
                                                   const __hip_bfloat16* __restrict__ Bh,
                                                   const __hip_bfloat16* __restrict__ Bl,
                                                   const float* __restrict__ resid,
                                                   float* __restrict__ C,
                                                   int M, int N, int K) {
    __shared__ __align__(16) short Ahs[2][128][32];   // 16 KB
    __shared__ __align__(16) short Als[2][128][32];   // 16 KB
    __shared__ __align__(16) short Bhs[2][64][32];    // 8 KB
    __shared__ __align__(16) short Bls[2][64][32];    // 8 KB -> 48 KB total
    int bm = blockIdx.y * 128, bn = blockIdx.x * 64;
    int t = threadIdx.x;
    int wave = t >> 6, lane = t & 63;
    int wm = (wave & 1) * 64, wn = (wave >> 1) * 32;
    int fr = lane & 15, quad = lane >> 4;
    int rA = wave * 32;            // A rows staged by this wave
    int rB = wave * 16;            // B rows staged by this wave
    int srow = lane >> 2;
    int schunk = (lane & 3) ^ ((lane >> 3) & 3);   // xor-swizzled 16B chunk
    const __hip_bfloat16* pAh0 = Ah + (size_t)(bm + rA + srow) * K + schunk * 8;
    const __hip_bfloat16* pAh1 = pAh0 + (size_t)16 * K;
    const __hip_bfloat16* pAl0 = Al + (size_t)(bm + rA + srow) * K + schunk * 8;
    const __hip_bfloat16* pAl1 = pAl0 + (size_t)16 * K;
    const __hip_bfloat16* pBh  = Bh + (size_t)(bn + rB + srow) * K + schunk * 8;
    const __hip_bfloat16* pBl  = Bl + (size_t)(bn + rB + srow) * K + schunk * 8;
    int ca = (quad ^ ((fr >> 1) & 3)) * 8;         // swizzled frag col (shorts)

    ldsdma16(&Ahs[0][rA][0],      pAh0);
    ldsdma16(&Ahs[0][rA + 16][0], pAh1);
    ldsdma16(&Als[0][rA][0],      pAl0);
    ldsdma16(&Als[0][rA + 16][0], pAl1);
    ldsdma16(&Bhs[0][rB][0],      pBh);
    ldsdma16(&Bls[0][rB][0],      pBl);

    f32x4 acc[4][2] = {};
    int NIT = K >> 5;
    for (int it = 0; it < NIT; it++) {
        int cur = it & 1;
        __syncthreads();
        if (it + 1 < NIT) {
            int k1 = (it + 1) << 5;
            int nxt = cur ^ 1;
            ldsdma16(&Ahs[nxt][rA][0],      pAh0 + k1);
            ldsdma16(&Ahs[nxt][rA + 16][0], pAh1 + k1);
            ldsdma16(&Als[nxt][rA][0],      pAl0 + k1);
            ldsdma16(&Als[nxt][rA + 16][0], pAl1 + k1);
            ldsdma16(&Bhs[nxt][rB][0],      pBh + k1);
            ldsdma16(&Bls[nxt][rB][0],      pBl + k1);
        }
        bf16x8 ah[4], bh[2], x[4];
        #pragma unroll
        for (int i = 0; i < 4; i++) ah[i] = *(const bf16x8*)&Ahs[cur][wm + i * 16 + fr][ca];
        #pragma unroll
        for (int i = 0; i < 2; i++) bh[i] = *(const bf16x8*)&Bhs[cur][wn + i * 16 + fr][ca];
        #pragma unroll
        for (int mi = 0; mi < 4; mi++)
            #pragma unroll
            for (int ni = 0; ni < 2; ni++)
                acc[mi][ni] = __builtin_amdgcn_mfma_f32_16x16x32_bf16(ah[mi], bh[ni], acc[mi][ni], 0, 0, 0);
        #pragma unroll
        for (int i = 0; i < 2; i++) x[i] = *(const bf16x8*)&Bls[cur][wn + i * 16 + fr][ca];
        #pragma unroll
        for (int mi = 0; mi < 4; mi++)
            #pragma unroll
            for (int ni = 0; ni < 2; ni++)
                acc[mi][ni] = __builtin_amdgcn_mfma_f32_16x16x32_bf16(ah[mi], x[ni], acc[mi][ni], 0, 0, 0);
        #pragma unroll
        for (int i = 0; i < 4; i++) x[i] = *(const bf16x8*)&Als[cur][wm + i * 16 + fr][ca];
        #pragma unroll
        for (int mi = 0; mi < 4; mi++)
            #pragma unroll
            for (int ni = 0; ni < 2; ni++)
                acc[mi][ni] = __builtin_amdgcn_mfma_f32_16x16x32_bf16(x[mi], bh[ni], acc[mi][ni], 0, 0, 0);
    }
    int rq = quad * 4;
    #pragma unroll
    for (int mi = 0; mi < 4; mi++) {
        #pragma unroll
        for (int r = 0; r < 4; r++) {
            size_t rowo = (size_t)(bm + wm + mi * 16 + rq + r) * N + bn + wn;
            #pragma unroll
            for (int ni = 0; ni < 2; ni++) {
                float v = acc[mi][ni][r];
                size_t o = rowo + ni * 16 + fr;
                if (resid) v += resid[o];
                C[o] = v;
            }
        }
    }
}

// ---------------------------------------------------------------- QKV GEMM with fused RoPE + split-bf16 epilogue
__global__ __launch_bounds__(256) void gemm_qkv_rope(const __hip_bfloat16* __restrict__ Ah,
                                                     const __hip_bfloat16* __restrict__ Al,
                                                     const __hip_bfloat16* __restrict__ Bh,
                                                     const __hip_bfloat16* __restrict__ Bl,
                                                     const float* __restrict__ fc,
                                                     __hip_bfloat16* __restrict__ qh, __hip_bfloat16* __restrict__ ql,
                                                     __hip_bfloat16* __restrict__ kh, __hip_bfloat16* __restrict__ kl,
                                                     __hip_bfloat16* __restrict__ vh, __hip_bfloat16* __restrict__ vl) {
    const int K = HS;
    __shared__ __align__(16) short Ahs[2][128][32];
    __shared__ __align__(16) short Als[2][128][32];
    __shared__ __align__(16) short Bhs[2][64][32];
    __shared__ __align__(16) short Bls[2][64][32];
    int bm = blockIdx.y * 128, bn = blockIdx.x * 64;
    int t = threadIdx.x;
    int wave = t >> 6, lane = t & 63;
    int wm = (wave & 1) * 64, wn = (wave >> 1) * 32;
    int fr = lane & 15, quad = lane >> 4;
    int rA = wave * 32;
    int rB = wave * 16;
    int srow = lane >> 2;
    int schunk = (lane & 3) ^ ((lane >> 3) & 3);
    const __hip_bfloat16* pAh0 = Ah + (size_t)(bm + rA + srow) * K + schunk * 8;
    const __hip_bfloat16* pAh1 = pAh0 + (size_t)16 * K;
    const __hip_bfloat16* pAl0 = Al + (size_t)(bm + rA + srow) * K + schunk * 8;
    const __hip_bfloat16* pAl1 = pAl0 + (size_t)16 * K;
    const __hip_bfloat16* pBh  = Bh + (size_t)(bn + rB + srow) * K + schunk * 8;
    const __hip_bfloat16* pBl  = Bl + (size_t)(bn + rB + srow) * K + schunk * 8;
    int ca = (quad ^ ((fr >> 1) & 3)) * 8;

    ldsdma16(&Ahs[0][rA][0],      pAh0);
    ldsdma16(&Ahs[0][rA + 16][0], pAh1);
    ldsdma16(&Als[0][rA][0],      pAl0);
    ldsdma16(&Als[0][rA + 16][0], pAl1);
    ldsdma16(&Bhs[0][rB][0],      pBh);
    ldsdma16(&Bls[0][rB][0],      pBl);

    f32x4 acc[4][2] = {};
    const int NIT = K >> 5;
    for (int it = 0; it < NIT; it++) {
        int cur = it & 1;
        __syncthreads();
        if (it + 1 < NIT) {
            int k1 = (it + 1) << 5;
            int nxt = cur ^ 1;
            ldsdma16(&Ahs[nxt][rA][0],      pAh0 + k1);
            ldsdma16(&Ahs[nxt][rA + 16][0], pAh1 + k1);
            ldsdma16(&Als[nxt][rA][0],      pAl0 + k1);
            ldsdma16(&Als[nxt][rA + 16][0], pAl1 + k1);
            ldsdma16(&Bhs[nxt][rB][0],      pBh + k1);
            ldsdma16(&Bls[nxt][rB][0],      pBl + k1);
        }
        bf16x8 ah[4], bh[2], x[4];
        #pragma unroll
        for (int i = 0; i < 4; i++) ah[i] = *(const bf16x8*)&Ahs[cur][wm + i * 16 + fr][ca];
        #pragma unroll
        for (int i = 0; i < 2; i++) bh[i] = *(const bf16x8*)&Bhs[cur][wn + i * 16 + fr][ca];
        #pragma unroll
        for (int mi = 0; mi < 4; mi++)
            #pragma unroll
            for (int ni = 0; ni < 2; ni++)
                acc[mi][ni] = __builtin_amdgcn_mfma_f32_16x16x32_bf16(ah[mi], bh[ni], acc[mi][ni], 0, 0, 0);
        #pragma unroll
        for (int i = 0; i < 2; i++) x[i] = *(const bf16x8*)&Bls[cur][wn + i * 16 + fr][ca];
        #pragma unroll
        for (int mi = 0; mi < 4; mi++)
            #pragma unroll
            for (int ni = 0; ni < 2; ni++)
                acc[mi][ni] = __builtin_amdgcn_mfma_f32_16x16x32_bf16(ah[mi], x[ni], acc[mi][ni], 0, 0, 0);
        #pragma unroll
        for (int i = 0; i < 4; i++) x[i] = *(const bf16x8*)&Als[cur][wm + i * 16 + fr][ca];
        #pragma unroll
        for (int mi = 0; mi < 4; mi++)
            #pragma unroll
            for (int ni = 0; ni < 2; ni++)
                acc[mi][ni] = __builtin_amdgcn_mfma_f32_16x16x32_bf16(x[mi], bh[ni], acc[mi][ni], 0, 0, 0);
    }
    // epilogue: block-uniform q/k/v selection (bn is a 64-aligned stripe)
    __hip_bfloat16 *dh, *dl;
    int cbase;
    bool dorope;
    if (bn < 1024)      { dh = qh; dl = ql; cbase = bn;        dorope = true;  }
    else if (bn < 2048) { dh = kh; dl = kl; cbase = bn - 1024; dorope = true;  }
    else                { dh = vh; dl = vl; cbase = bn - 2048; dorope = false; }
    float sgn = (fr & 1) ? 1.f : -1.f;
    int rq = quad * 4;
    #pragma unroll
    for (int mi = 0; mi < 4; mi++) {
        #pragma unroll
        for (int r = 0; r < 4; r++) {
            int trow = bm + wm + mi * 16 + rq + r;
            int s = trow & (SEQ - 1);
            size_t ob = (size_t)trow * HS + cbase;
            #pragma unroll
            for (int ni = 0; ni < 2; ni++) {
                float v = acc[mi][ni][r];
                int colh = wn + ni * 16 + fr;          // 0..63 within stripe = head pos
                float outv;
                if (dorope) {
                    float p = __shfl_xor(v, 1);
                    const float* fb = fc + (size_t)s * HDIM + (colh & ~1);
                    float cr = fb[0], ci = fb[1];
                    outv = v * cr + sgn * (p * ci);
                } else {
                    outv = v;
                }
                __hip_bfloat16 hi = __float2bfloat16(outv);
                __hip_bfloat16 lo = __float2bfloat16(outv - __bfloat162float(hi));
                dh[ob + colh] = hi;
                dl[ob + colh] = lo;
            }
        }
    }
}

// ---------------------------------------------------------------- split-K flash attention, MFMA split-bf16
__global__ __launch_bounds__(256) void attn_partial(
        const __hip_bfloat16* __restrict__ qh, const __hip_bfloat16* __restrict__ ql,
        const __hip_bfloat16* __restrict__ kh, const __hip_bfloat16* __restrict__ kl,
        const __hip_bfloat16* __restrict__ vh, const __hip_bfloat16* __restrict__ vl,
        float* __restrict__ po, float* __restrict__ pm_g, float* __restrict__ pl_g) {
    int c = blockIdx.x, qt = blockIdx.y;
    int nc = (qt + 4) >> 2;
    if (c >= nc) return;
    int bh = blockIdx.z;
    int b = bh >> 4, h = bh & 15;
    int t0 = c * 4, t1 = min(t0 + 4, qt + 1);
    int tid = threadIdx.x;
    int wave = tid >> 6, lane = tid & 63;
    int fr = lane & 15, quad = lane >> 4;
    int w16 = wave * 16;
    __shared__ __align__(16) short Qh[64][PAD], Ql[64][PAD];
    __shared__ __align__(16) short KPh[64][PAD], KPl[64][PAD];
    __shared__ __align__(16) short Vhs[64][PAD], Vls[64][PAD];
    size_t hoff = (size_t)h * HDIM;
    int sr = tid >> 2, sg = tid & 3;
    {
        const __hip_bfloat16* qp  = qh + (size_t)(b * SEQ + qt * 64 + sr) * HS + hoff;
        const __hip_bfloat16* qp2 = ql + (size_t)(b * SEQ + qt * 64 + sr) * HS + hoff;
        *(uint4*)&Qh[sr][sg * 8]       = *(const uint4*)(qp + sg * 8);
        *(uint4*)&Qh[sr][(sg + 4) * 8] = *(const uint4*)(qp + (sg + 4) * 8);
        *(uint4*)&Ql[sr][sg * 8]       = *(const uint4*)(qp2 + sg * 8);
        *(uint4*)&Ql[sr][(sg + 4) * 8] = *(const uint4*)(qp2 + (sg + 4) * 8);
    }
    f32x4 o[4] = {};
    float mrow[4], lrow[4];
    #pragma unroll
    for (int i = 0; i < 4; i++) { mrow[i] = -1e30f; lrow[i] = 0.f; }
    int key0 = (tid & 31) * 2, ds = tid >> 5;
    __syncthreads();

    for (int kt = t0; kt < t1; kt++) {
        int kbase = kt * 64;
        {
            const __hip_bfloat16* kp  = kh + (size_t)(b * SEQ + kbase + sr) * HS + hoff;
            const __hip_bfloat16* kp2 = kl + (size_t)(b * SEQ + kbase + sr) * HS + hoff;
            *(uint4*)&KPh[sr][sg * 8]       = *(const uint4*)(kp + sg * 8);
            *(uint4*)&KPh[sr][(sg + 4) * 8] = *(const uint4*)(kp + (sg + 4) * 8);
            *(uint4*)&KPl[sr][sg * 8]       = *(const uint4*)(kp2 + sg * 8);
            *(uint4*)&KPl[sr][(sg + 4) * 8] = *(const uint4*)(kp2 + (sg + 4) * 8);
        }
        {
            const __hip_bfloat16* v0 = vh + (size_t)(b * SEQ + kbase + key0) * HS + hoff + ds * 8;
            uint4 A = *(const uint4*)v0;
            uint4 Bv = *(const uint4*)(v0 + HS);
            const unsigned short* ap = (const unsigned short*)&A;
            const unsigned short* bp = (const unsigned short*)&Bv;
            #pragma unroll
            for (int j = 0; j < 8; j++)
                *(unsigned*)&Vhs[ds * 8 + j][key0] = (unsigned)ap[j] | ((unsigned)bp[j] << 16);
            const __hip_bfloat16* v2 = vl + (size_t)(b * SEQ + kbase + key0) * HS + hoff + ds * 8;
            uint4 A2 = *(const uint4*)v2;
            uint4 B2 = *(const uint4*)(v2 + HS);
            const unsigned short* ap2 = (const unsigned short*)&A2;
            const unsigned short* bp2 = (const unsigned short*)&B2;
            #pragma unroll
            for (int j = 0; j < 8; j++)
                *(unsigned*)&Vls[ds * 8 + j][key0] = (unsigned)ap2[j] | ((unsigned)bp2[j] << 16);
        }
        __syncthreads();

        f32x4 s[4] = {};
        #pragma unroll
        for (int ks = 0; ks < 2; ks++) {
            bf16x8 a_h = *(const bf16x8*)&Qh[w16 + fr][quad * 8 + ks * 32];
            bf16x8 a_l = *(const bf16x8*)&Ql[w16 + fr][quad * 8 + ks * 32];
            #pragma unroll
            for (int ni = 0; ni < 4; ni++) {
                bf16x8 b_h = *(const bf16x8*)&KPh[ni * 16 + fr][quad * 8 + ks * 32];
                bf16x8 b_l = *(const bf16x8*)&KPl[ni * 16 + fr][quad * 8 + ks * 32];
                s[ni] = __builtin_amdgcn_mfma_f32_16x16x32_bf16(a_h, b_h, s[ni], 0, 0, 0);
                s[ni] = __builtin_amdgcn_mfma_f32_16x16x32_bf16(a_h, b_l, s[ni], 0, 0, 0);
                s[ni] = __builtin_amdgcn_mfma_f32_16x16x32_bf16(a_l, b_h, s[ni], 0, 0, 0);
            }
        }
        int qg = qt * 64 + w16 + quad * 4;
        #pragma unroll
        for (int ni = 0; ni < 4; ni++) {
            int kg = kbase + ni * 16 + fr;
            #pragma unroll
            for (int r = 0; r < 4; r++)
                s[ni][r] = (kg > qg + r) ? -1e9f : s[ni][r] * 0.125f;
        }
        #pragma unroll
        for (int r = 0; r < 4; r++) {
            float mx = fmaxf(fmaxf(s[0][r], s[1][r]), fmaxf(s[2][r], s[3][r]));
            #pragma unroll
            for (int wd = 1; wd < 16; wd <<= 1) mx = fmaxf(mx, __shfl_xor(mx, wd));
            float nm = fmaxf(mrow[r], mx);
            float alpha = __expf(mrow[r] - nm);
            float rs = 0.f;
            #pragma unroll
            for (int ni = 0; ni < 4; ni++) { float e = __expf(s[ni][r] - nm); s[ni][r] = e; rs += e; }
            #pragma unroll
            for (int wd = 1; wd < 16; wd <<= 1) rs += __shfl_xor(rs, wd);
            lrow[r] = lrow[r] * alpha + rs;
            mrow[r] = nm;
            o[0][r] *= alpha; o[1][r] *= alpha; o[2][r] *= alpha; o[3][r] *= alpha;
        }
        __syncthreads();
        #pragma unroll
        for (int ni = 0; ni < 4; ni++)
            #pragma unroll
            for (int r = 0; r < 4; r++) {
                float pv = s[ni][r];
                __hip_bfloat16 hi = __float2bfloat16(pv);
                __hip_bfloat16 lo = __float2bfloat16(pv - __bfloat162float(hi));
                KPh[w16 + quad * 4 + r][ni * 16 + fr] = *(short*)&hi;
                KPl[w16 + quad * 4 + r][ni * 16 + fr] = *(short*)&lo;
            }
        #pragma unroll
        for (int ks = 0; ks < 2; ks++) {
            bf16x8 p_h = *(const bf16x8*)&KPh[w16 + fr][quad * 8 + ks * 32];
            bf16x8 p_l = *(const bf16x8*)&KPl[w16 + fr][quad * 8 + ks * 32];
            #pragma unroll
            for (int ni = 0; ni < 4; ni++) {
                bf16x8 v_h = *(const bf16x8*)&Vhs[ni * 16 + fr][quad * 8 + ks * 32];
                bf16x8 v_l = *(const bf16x8*)&Vls[ni * 16 + fr][quad * 8 + ks * 32];
                o[ni] = __builtin_amdgcn_mfma_f32_16x16x32_bf16(p_h, v_h, o[ni], 0, 0, 0);
                o[ni] = __builtin_amdgcn_mfma_f32_16x16x32_bf16(p_h, v_l, o[ni], 0, 0, 0);
                o[ni] = __builtin_amdgcn_mfma_f32_16x16x32_bf16(p_l, v_h, o[ni], 0, 0, 0);
            }
        }
        __syncthreads();
    }
    int pidx = (bh * 16 + qt) * 4 + c;
    float* pob = po + (size_t)pidx * 4096;
    #pragma unroll
    for (int ni = 0; ni < 4; ni++)
        #pragma unroll
        for (int r = 0; r < 4; r++)
            pob[(w16 + quad * 4 + r) * 64 + ni * 16 + fr] = o[ni][r];
    if (fr == 0) {
        #pragma unroll
        for (int r = 0; r < 4; r++) {
            pm_g[pidx * 64 + w16 + quad * 4 + r] = mrow[r];
            pl_g[pidx * 64 + w16 + quad * 4 + r] = lrow[r];
        }
    }
}

// ---------------------------------------------------------------- merge partials -> ctx as split bf16
__global__ void attn_merge(const float* __restrict__ po, const float* __restrict__ pm,
                           const float* __restrict__ pl,
                           __hip_bfloat16* __restrict__ ch, __hip_bfloat16* __restrict__ cl) {
    int qt = blockIdx.x, h = blockIdx.y, b = blockIdx.z;
    int bh = b * 16 + h;
    int nc = (qt + 4) >> 2;
    int base = (bh * 16 + qt) * 4;
    int tid = threadIdx.x;
    int r  = tid >> 2;
    int d0 = (tid & 3) * 16;
    float mstar = -1e30f;
    for (int c = 0; c < nc; c++) mstar = fmaxf(mstar, pm[(base + c) * 64 + r]);
    float a[4];
    float lsum = 0.f;
    for (int c = 0; c < nc; c++) {
        a[c] = __expf(pm[(base + c) * 64 + r] - mstar);
        lsum += a[c] * pl[(base + c) * 64 + r];
    }
    float inv = 1.f / lsum;
    size_t crow = (size_t)(b * SEQ + qt * 64 + r) * HS + h * HDIM;
    for (int dd = 0; dd < 16; dd += 4) {
        float4 acc = make_float4(0.f, 0.f, 0.f, 0.f);
        for (int c = 0; c < nc; c++) {
            float4 v = *(const float4*)(po + (size_t)(base + c) * 4096 + r * 64 + d0 + dd);
            acc.x += a[c] * v.x; acc.y += a[c] * v.y;
            acc.z += a[c] * v.z; acc.w += a[c] * v.w;
        }
        float vs[4] = {acc.x * inv, acc.y * inv, acc.z * inv, acc.w * inv};
        #pragma unroll
        for (int j = 0; j < 4; j++) {
            __hip_bfloat16 hi = __float2bfloat16(vs[j]);
            ch[crow + d0 + dd + j] = hi;
            cl[crow + d0 + dd + j] = __float2bfloat16(vs[j] - __bfloat162float(hi));
        }
    }
}

// ---------------------------------------------------------------- offsets + block table
__global__ void offsets_kernel(const int* __restrict__ cnt, int* __restrict__ off,
                               int* __restrict__ blk_e, int* __restrict__ blk_r) {
    if (threadIdx.x == 0) {
        int o = 0, n = 0;
        for (int e = 0; e < NEXP; e++) {
            off[e] = o;
            for (int bm = 0; bm < cnt[e]; bm += 128) { blk_e[n] = e; blk_r[n] = bm; n++; }
            o += cnt[e];
        }
        for (; n < MAXBLK; n++) { blk_e[n] = -1; blk_r[n] = 0; }
    }
}

__global__ void scatter_kernel(const int* __restrict__ topEk, int* __restrict__ fill,
                               const int* __restrict__ off, const float* __restrict__ topW,
                               int* __restrict__ tok_list, int* __restrict__ inv) {
    int idx = blockIdx.x * 256 + threadIdx.x;
    int e = topEk[idx];
    int slot = atomicAdd(&fill[e], 1);
    int gidx = off[e] + slot;
    tok_list[gidx] = idx >> 1;
    inv[idx] = gidx;
}

// ---------------------------------------------------------------- MoE up-proj, 128x64 tile, dbuf DMA
__global__ __launch_bounds__(256) void moe_up_mfma(const __hip_bfloat16* __restrict__ Abf,
                                                   const __hip_bfloat16* __restrict__ B1T,
                                                   const __hip_bfloat16* __restrict__ B3T,
                                                   __hip_bfloat16* __restrict__ g,
                                                   const int* __restrict__ cnt,
                                                   const int* __restrict__ off,
                                                   const int* __restrict__ tok_list,
                                                   const int* __restrict__ blk_e,
                                                   const int* __restrict__ blk_r) {
    int e = blk_e[blockIdx.y];
    if (e < 0) return;
    int bm = blk_r[blockIdx.y];
    int ce = cnt[e], oe = off[e];
    int bn = blockIdx.x * 64;
    const __hip_bfloat16* b1 = B1T + (size_t)e * IS * HS;   // [IS][HS]
    const __hip_bfloat16* b3 = B3T + (size_t)e * IS * HS;

    __shared__ __align__(16) short As[2][128][32];    // 16 KB
    __shared__ __align__(16) short B1s[2][64][32];    // 8 KB
    __shared__ __align__(16) short B3s[2][64][32];    // 8 KB -> 32 KB

    int t = threadIdx.x;
    int wave = t >> 6, lane = t & 63;
    int wm = (wave & 1) * 64, wn = (wave >> 1) * 32;
    int fr = lane & 15, quad = lane >> 4;
    int rA = wave * 32, rB = wave * 16;
    int srow = lane >> 2;
    int schunk = (lane & 3) ^ ((lane >> 3) & 3);
    int tokA0 = tok_list[oe + min(bm + rA + srow, ce - 1)];
    int tokA1 = tok_list[oe + min(bm + rA + 16 + srow, ce - 1)];
    const __hip_bfloat16* pA0 = Abf + (size_t)tokA0 * HS + schunk * 8;
    const __hip_bfloat16* pA1 = Abf + (size_t)tokA1 * HS + schunk * 8;
    const __hip_bfloat16* pB1 = b1 + (size_t)(bn + rB + srow) * HS + schunk * 8;
    const __hip_bfloat16* pB3 = b3 + (size_t)(bn + rB + srow) * HS + schunk * 8;
    int ca = (quad ^ ((fr >> 1) & 3)) * 8;

    ldsdma16(&As[0][rA][0],      pA0);
    ldsdma16(&As[0][rA + 16][0], pA1);
    ldsdma16(&B1s[0][rB][0],     pB1);
    ldsdma16(&B3s[0][rB][0],     pB3);

    f32x4 acc1[4][2] = {};
    f32x4 acc3[4][2] = {};
    const int NIT = HS >> 5;
    for (int it = 0; it < NIT; it++) {
        int cur = it & 1;
        __syncthreads();
        if (it + 1 < NIT) {
            int k1 = (it + 1) << 5;
            int nxt = cur ^ 1;
            ldsdma16(&As[nxt][rA][0],      pA0 + k1);
            ldsdma16(&As[nxt][rA + 16][0], pA1 + k1);
            ldsdma16(&B1s[nxt][rB][0],     pB1 + k1);
            ldsdma16(&B3s[nxt][rB][0],     pB3 + k1);
        }
        bf16x8 a[4], f1[2], f3[2];
        #pragma unroll
        for (int i = 0; i < 4; i++) a[i] = *(const bf16x8*)&As[cur][wm + i * 16 + fr][ca];
        #pragma unroll
        for (int i = 0; i < 2; i++) {
            f1[i] = *(const bf16x8*)&B1s[cur][wn + i * 16 + fr][ca];
            f3[i] = *(const bf16x8*)&B3s[cur][wn + i * 16 + fr][ca];
        }
        #pragma unroll
        for (int mi = 0; mi < 4; mi++)
            #pragma unroll
            for (int ni = 0; ni < 2; ni++) {
                acc1[mi][ni] = __builtin_amdgcn_mfma_f32_16x16x32_bf16(a[mi], f1[ni], acc1[mi][ni], 0, 0, 0);
                acc3[mi][ni] = __builtin_amdgcn_mfma_f32_16x16x32_bf16(a[mi], f3[ni], acc3[mi][ni], 0, 0, 0);
            }
    }
    int rq = quad * 4;
    #pragma unroll
    for (int mi = 0; mi < 4; mi++) {
        #pragma unroll
        for (int r = 0; r < 4; r++) {
            int slot = bm + wm + mi * 16 + rq + r;
            if (slot < ce) {
                size_t rowo = (size_t)(oe + slot) * IS + bn + wn;
                #pragma unroll
                for (int ni = 0; ni < 2; ni++) {
                    float x1 = acc1[mi][ni][r];
                    float x3 = acc3[mi][ni][r];
                    float sv = (x1 / (1.f + __expf(-x1))) * x3;
                    g[rowo + ni * 16 + fr] = __float2bfloat16(sv);
                }
            }
        }
    }
}

// ---------------------------------------------------------------- MoE down-proj, 128x64 tile, split-K=2, scratch (no atomics)
__global__ __launch_bounds__(256) void moe_down_mfma(const __hip_bfloat16* __restrict__ g,
                                                     const __hip_bfloat16* __restrict__ B2T,
                                                     float* __restrict__ scr,
                                                     const int* __restrict__ cnt,
                                                     const int* __restrict__ off,
                                                     const int* __restrict__ blk_e,
                                                     const int* __restrict__ blk_r) {
    int e = blk_e[blockIdx.y];
    if (e < 0) return;
    int bm = blk_r[blockIdx.y];
    int ce = cnt[e], oe = off[e];
    int bn = blockIdx.x * 64;
    int kz = blockIdx.z * (IS / 2);           // split-K half
    const __hip_bfloat16* b2 = B2T + (size_t)e * HS * IS;   // [HS][IS]

    __shared__ __align__(16) short As[2][128][32];   // 16 KB
    __shared__ __align__(16) short Bs[2][64][32];    // 8 KB -> 24 KB

    int t = threadIdx.x;
    int wave = t >> 6, lane = t & 63;
    int wm = (wave & 1) * 64, wn = (wave >> 1) * 32;
    int fr = lane & 15, quad = lane >> 4;
    int rA = wave * 32, rB = wave * 16;
    int srow = lane >> 2;
    int schunk = (lane & 3) ^ ((lane >> 3) & 3);
    int ga0 = oe + min(bm + rA + srow, ce - 1);
    int ga1 = oe + min(bm + rA + 16 + srow, ce - 1);
    const __hip_bfloat16* pA0 = g + (size_t)ga0 * IS + kz + schunk * 8;
    const __hip_bfloat16* pA1 = g + (size_t)ga1 * IS + kz + schunk * 8;
    const __hip_bfloat16* pB  = b2 + (size_t)(bn + rB + srow) * IS + kz + schunk * 8;
    int ca = (quad ^ ((fr >> 1) & 3)) * 8;

    ldsdma16(&As[0][rA][0],      pA0);
    ldsdma16(&As[0][rA + 16][0], pA1);
    ldsdma16(&Bs[0][rB][0],      pB);

    f32x4 acc[4][2] = {};
    const int NIT = (IS / 2) >> 5;
    for (int it = 0; it < NIT; it++) {
        int cur = it & 1;
        __syncthreads();
        if (it + 1 < NIT) {
            int k1 = (it + 1) << 5;
            int nxt = cur ^ 1;
            ldsdma16(&As[nxt][rA][0],      pA0 + k1);
            ldsdma16(&As[nxt][rA + 16][0], pA1 + k1);
            ldsdma16(&Bs[nxt][rB][0],      pB + k1);
        }
        bf16x8 a[4], f[2];
        #pragma unroll
        for (int i = 0; i < 4; i++) a[i] = *(const bf16x8*)&As[cur][wm + i * 16 + fr][ca];
        #pragma unroll
        for (int i = 0; i < 2; i++) f[i] = *(const bf16x8*)&Bs[cur][wn + i * 16 + fr][ca];
        #pragma unroll
        for (int mi = 0; mi < 4; mi++)
            #pragma unroll
            for (int ni = 0; ni < 2; ni++)
                acc[mi][ni] = __builtin_amdgcn_mfma_f32_16x16x32_bf16(a[mi], f[ni], acc[mi][ni], 0, 0, 0);
    }
    int rq = quad * 4;
    #pragma unroll
    for (int mi = 0; mi < 4; mi++) {
        #pragma unroll
        for (int r = 0; r < 4; r++) {
            int slot = bm + wm + mi * 16 + rq + r;
            if (slot < ce) {
                int gidx = oe + slot;
                size_t rowo = (size_t)(blockIdx.z * NASSIGN + gidx) * HS + bn + wn;
                #pragma unroll
                for (int ni = 0; ni < 2; ni++)
                    scr[rowo + ni * 16 + fr] = acc[mi][ni][r];
            }
        }
    }
}

// ---------------------------------------------------------------- gather: out[t] = h[t] + sum_k w_k * (p0[g_k] + p1[g_k])
__global__ void moe_gather(const float* __restrict__ scr, const int* __restrict__ inv,
                           const float* __restrict__ topW, float* __restrict__ out) {
    int t = blockIdx.x;
    int c = threadIdx.x * 4;
    int g0 = inv[2 * t], g1 = inv[2 * t + 1];
    float w0 = topW[2 * t], w1 = topW[2 * t + 1];
    size_t o = (size_t)t * HS + c;
    float4 h4 = *(const float4*)(out + o);
    float4 a0 = *(const float4*)(scr + (size_t)g0 * HS + c);
    float4 a1 = *(const float4*)(scr + (size_t)(NASSIGN + g0) * HS + c);
    float4 b0 = *(const float4*)(scr + (size_t)g1 * HS + c);
    float4 b1 = *(const float4*)(scr + (size_t)(NASSIGN + g1) * HS + c);
    float4 r;
    r.x = h4.x + w0 * (a0.x + a1.x) + w1 * (b0.x + b1.x);
    r.y = h4.y + w0 * (a0.y + a1.y) + w1 * (b0.y + b1.y);
    r.z = h4.z + w0 * (a0.z + a1.z) + w1 * (b0.z + b1.z);
    r.w = h4.w + w0 * (a0.w + a1.w) + w1 * (b0.w + b1.w);
    *(float4*)(out + o) = r;
}

// ---------------------------------------------------------------- launch
extern "C" void kernel_launch(void* const* d_in, const int* in_sizes, int n_in,
                              void* d_out, int out_size, void* d_ws, size_t ws_size,
                              hipStream_t stream) {
    const float* x   = (const float*)d_in[0];
    const float* anw = (const float*)d_in[1];
    const float* fnw = (const float*)d_in[2];
    const float* wq  = (const float*)d_in[3];
    const float* wk  = (const float*)d_in[4];
    const float* wv  = (const float*)d_in[5];
    const float* wo  = (const float*)d_in[6];
    const float* rw  = (const float*)d_in[7];
    const float* w1  = (const float*)d_in[8];
    const float* w3  = (const float*)d_in[9];
    const float* w2  = (const float*)d_in[10];
    const float* fc  = (const float*)d_in[11];
    float* out = (float*)d_out;

    char* ws = (char*)d_ws;
    const size_t MB = 1024 * 1024;
    __hip_bfloat16* xn_h  = (__hip_bfloat16*)(ws + 0 * MB);
    __hip_bfloat16* xn_l  = (__hip_bfloat16*)(ws + 4 * MB);
    __hip_bfloat16* WqT_h = (__hip_bfloat16*)(ws + 32 * MB);
    __hip_bfloat16* WqT_l = (__hip_bfloat16*)(ws + 38 * MB);
    __hip_bfloat16* woT_h = (__hip_bfloat16*)(ws + 44 * MB);
    __hip_bfloat16* woT_l = (__hip_bfloat16*)(ws + 46 * MB);
    float*          po    = (float*)(ws + 48 * MB);      // attn partials [48,80)
    float*          pm    = (float*)(ws + 82 * MB);
    float*          plb   = (float*)(ws + 83 * MB);
    __hip_bfloat16* ctx_h = (__hip_bfloat16*)(ws + 84 * MB);
    __hip_bfloat16* ctx_l = (__hip_bfloat16*)(ws + 88 * MB);
    __hip_bfloat16* qhb   = (__hip_bfloat16*)(ws + 92 * MB);
    __hip_bfloat16* qlb   = (__hip_bfloat16*)(ws + 96 * MB);
    __hip_bfloat16* khb   = (__hip_bfloat16*)(ws + 100 * MB);
    __hip_bfloat16* klb   = (__hip_bfloat16*)(ws + 104 * MB);
    __hip_bfloat16* vhb   = (__hip_bfloat16*)(ws + 108 * MB);
    __hip_bfloat16* vlb   = (__hip_bfloat16*)(ws + 112 * MB);
    __hip_bfloat16* hn_bf = (__hip_bfloat16*)(ws + 8 * MB);    // [8,12)
    __hip_bfloat16* w1T   = (__hip_bfloat16*)(ws + 12 * MB);   // [12,44)  dead after moe_up
    float*          dscr  = (float*)(ws + 12 * MB);            // [12,44)  moe_down scratch (reuses w1T)
    __hip_bfloat16* w3T   = (__hip_bfloat16*)(ws + 44 * MB);   // [44,76)
    __hip_bfloat16* w2T   = (__hip_bfloat16*)(ws + 76 * MB);   // [76,108)
    __hip_bfloat16* gact  = (__hip_bfloat16*)(ws + 108 * MB);  // [108,124)
    int* ibase    = (int*)(ws + 124 * MB);
    int* cnt      = ibase;                 // 8
    int* fill     = ibase + 8;             // 8
    int* off      = ibase + 16;            // 8
    int* blk_e    = ibase + 24;            // 40
    int* blk_r    = ibase + 64;            // 40
    int* topEk    = ibase + 128;           // 4096
    int* tok_list = ibase + 128 + NASSIGN; // 4096
    float* topW   = (float*)(ibase + 128 + 2 * NASSIGN);
    int*   inv    = ibase + 128 + 3 * NASSIGN;   // 4096: assignment index per (token, k)

    // ---- attention half ----
    transpose_split4<<<dim3(128, 1, 4), 256, 0, stream>>>(
        wq, wk, wv, wo, WqT_h, WqT_l, woT_h, woT_l, cnt);
    rmsnorm_split<<<NTOK, 256, 0, stream>>>(x, anw, xn_h, xn_l);

    gemm_qkv_rope<<<dim3(QKVW / 64, NTOK / 128), 256, 0, stream>>>(
        xn_h, xn_l, WqT_h, WqT_l, fc, qhb, qlb, khb, klb, vhb, vlb);

    attn_partial<<<dim3(4, 16, 32), 256, 0, stream>>>(qhb, qlb, khb, klb, vhb, vlb, po, pm, plb);
    attn_merge<<<dim3(16, 16, 2), 256, 0, stream>>>(po, pm, plb, ctx_h, ctx_l);

    gemm_bf16x3<<<dim3(HS / 64, NTOK / 128), 256, 0, stream>>>(
        ctx_h, ctx_l, woT_h, woT_l, x, out, NTOK, HS, HS);   // out = h = x + ctx@wo

    // ---- MoE half (routed top-2, bf16 MFMA experts) ----
    rmsnorm_router<<<NTOK, 256, 0, stream>>>(out, fnw, rw, hn_bf, cnt, topEk, topW);
    transpose_b64_all<<<dim3(256, 8, 3), 256, 0, stream>>>(
        w1, w3, w2, w1T, w3T, w2T);

    offsets_kernel<<<1, 64, 0, stream>>>(cnt, off, blk_e, blk_r);
    scatter_kernel<<<NASSIGN / 256, 256, 0, stream>>>(topEk, fill, off, topW, tok_list, inv);

    moe_up_mfma<<<dim3(IS / 64, MAXBLK), 256, 0, stream>>>(
        hn_bf, w1T, w3T, gact, cnt, off, tok_list, blk_e, blk_r);
    moe_down_mfma<<<dim3(HS / 64, MAXBLK, 2), 256, 0, stream>>>(
        gact, w2T, dscr, cnt, off, blk_e, blk_r);
    moe_gather<<<NTOK, 256, 0, stream>>>(dscr, inv, topW, out);
}